// Round 7
// baseline (670.766 us; speedup 1.0000x reference)
//
#include <hip/hip_runtime.h>
#include <hip/hip_bf16.h>
#include <cstdint>
#include <cstddef>

typedef __hip_bfloat16 bf16;
typedef __bf16 bf16x8 __attribute__((ext_vector_type(8)));
typedef float f32x4 __attribute__((ext_vector_type(4)));

#define S_D 30
#define C_D 16
#define H_D 768
#define EPS_F 1e-5f

// ------------------------------------------------------------------
// prep: bf16 transposed weight concats + folded biases (segment-concat
// k-order: Wcat k<768 -> W_s, else seg=(k-768)/768 -> W_r[seg];
// Wcat2 k<768 -> W_s, else {W_r0, W_r2}).
// ------------------------------------------------------------------
__global__ __launch_bounds__(256) void prep_weights_k(
    const float* __restrict__ W_r, const float* __restrict__ b_r,
    const float* __restrict__ W_s, const float* __restrict__ b_s,
    const float* __restrict__ W_g,
    bf16* __restrict__ Wcat, bf16* __restrict__ Wg, bf16* __restrict__ Wcat2,
    float* __restrict__ bslot, float* __restrict__ bcls)
{
  int id = blockIdx.x*256 + threadIdx.x;
  const int n1 = 768*3840, n2 = 768*1536, n3 = 768*2304;
  if (id < n1) {
    int n = id / 3840, k = id % 3840, seg = k / 768, kk = k % 768;
    float w = (seg == 0) ? W_s[kk*768 + n] : W_r[((size_t)(seg-1)*768 + kk)*768 + n];
    Wcat[id] = __float2bfloat16(w);
  } else if (id < n1 + n2) {
    int j = id - n1; int n = j / 1536, k = j % 1536;
    Wg[j] = __float2bfloat16(W_g[(size_t)k*768 + n]);
  } else if (id < n1 + n2 + n3) {
    int j = id - n1 - n2; int n = j / 2304, k = j % 2304, seg = k / 768, kk = k % 768;
    float w = (seg == 0) ? W_s[kk*768 + n]
            : (seg == 1 ? W_r[(size_t)kk*768 + n] : W_r[((size_t)2*768 + kk)*768 + n]);
    Wcat2[j] = __float2bfloat16(w);
  } else if (id < n1 + n2 + n3 + 768) {
    int n = id - n1 - n2 - n3;
    bslot[n] = b_s[n] + b_r[n] + b_r[768+n] + b_r[2*768+n] + b_r[3*768+n];
    bcls[n]  = b_s[n] + b_r[n] + b_r[2*768+n];
  }
}

// ------------------------------------------------------------------
// prep: per-batch aggregation matrices, bf16, padded.
// Cmat [512][160][64]: row m<120: s=m>>2, seg=m&3:
//   seg0: cols 30+c = a_cur_norm[s][c]   (row-sum norm)  -> W_r0
//   seg1: cols j    = a_slot_norm[s][j]                  -> W_r1
//   seg2: cols 30+c = a_last_norm[s][c]                  -> W_r2
//   seg3: cols j    = a_dom_norm[s][j]                   -> W_r3
// rows 120..151: c=(m-120)>>1, seg&1: cols j = a_cur/a_last col-norm.
// rows 152..159 and cols 46..63: zero.
// Cmat2 [512][32][32]: rows 2c / 2c+1 = a_cur / a_last col-norm.
// ------------------------------------------------------------------
__global__ __launch_bounds__(64) void prep_cmat_k(
    const float* __restrict__ a_cur, const float* __restrict__ a_slot,
    const float* __restrict__ a_last, const float* __restrict__ a_dom,
    bf16* __restrict__ Cm, bf16* __restrict__ Cm2)
{
  __shared__ float ivr[4][S_D];
  __shared__ float ivc[2][C_D];
  int b = blockIdx.x, t = threadIdx.x;
  const float* ac  = a_cur  + (size_t)b*480;
  const float* as_ = a_slot + (size_t)b*900;
  const float* al  = a_last + (size_t)b*480;
  const float* ad  = a_dom  + (size_t)b*900;
  if (t < S_D) {
    float s1=0, s2=0, s3=0, s4=0;
    for (int c=0;c<C_D;c++){ s1+=ac[t*C_D+c]; s3+=al[t*C_D+c]; }
    for (int j=0;j<S_D;j++){ s2+=as_[t*S_D+j]; s4+=ad[t*S_D+j]; }
    ivr[0][t]=1.f/(s1+EPS_F); ivr[1][t]=1.f/(s2+EPS_F);
    ivr[2][t]=1.f/(s3+EPS_F); ivr[3][t]=1.f/(s4+EPS_F);
  } else if (t < S_D + C_D) {
    int c = t - S_D; float s1=0, s3=0;
    for (int j=0;j<S_D;j++){ s1+=ac[j*C_D+c]; s3+=al[j*C_D+c]; }
    ivc[0][c]=1.f/(s1+EPS_F); ivc[1][c]=1.f/(s3+EPS_F);
  }
  __syncthreads();
  for (int m = t; m < 160; m += 64) {
    bf16* row = Cm + ((size_t)b*160 + m)*64;
    uint4 z = {0,0,0,0};
    #pragma unroll
    for (int q = 0; q < 8; ++q) *(uint4*)(row + q*8) = z;
    if (m < 120) {
      int s = m >> 2, g = m & 3;
      if (g == 0)      { float iv=ivr[0][s]; for (int c=0;c<C_D;c++) row[30+c]=__float2bfloat16(ac[s*C_D+c]*iv); }
      else if (g == 1) { float iv=ivr[1][s]; for (int j=0;j<S_D;j++) row[j]   =__float2bfloat16(as_[s*S_D+j]*iv); }
      else if (g == 2) { float iv=ivr[2][s]; for (int c=0;c<C_D;c++) row[30+c]=__float2bfloat16(al[s*C_D+c]*iv); }
      else             { float iv=ivr[3][s]; for (int j=0;j<S_D;j++) row[j]   =__float2bfloat16(ad[s*S_D+j]*iv); }
    } else if (m < 152) {
      int c = (m-120) >> 1, g = (m-120) & 1;
      if (g == 0) { float iv=ivc[0][c]; for (int j=0;j<S_D;j++) row[j]=__float2bfloat16(ac[j*C_D+c]*iv); }
      else        { float iv=ivc[1][c]; for (int j=0;j<S_D;j++) row[j]=__float2bfloat16(al[j*C_D+c]*iv); }
    }
  }
  if (t < 32) {
    bf16* row = Cm2 + ((size_t)b*32 + t)*32;
    uint4 z = {0,0,0,0};
    #pragma unroll
    for (int q = 0; q < 4; ++q) *(uint4*)(row + q*8) = z;
    int c = t >> 1, g = t & 1;
    float iv = g ? ivc[1][c] : ivc[0][c];
    const float* A = g ? al : ac;
    for (int j = 0; j < S_D; ++j) row[j] = __float2bfloat16(A[j*C_D+c]*iv);
  }
}

// ------------------------------------------------------------------
// aggregation as MFMA batched GEMM: Z[b] = Cmat[b] @ X[b], no LDS.
// Block = (batch, half of 768 cols); 4 waves x 96 cols x 6 n-tiles.
// A-frags cached in VGPRs; B-frags gathered per-k (row-coalesced) from
// slots/cls f32 (CVT=1, also writes Gin right halves when WG=1) or from
// Xo bf16 (CVT=0). K padded with zero Cmat cols (clamped source rows).
// ------------------------------------------------------------------
template<int MT, int KS, int CVT, int WG>
__global__ __launch_bounds__(256) void aggmm_k(
    const bf16* __restrict__ Cm, const float* __restrict__ s0,
    const float* __restrict__ s1, const bf16* __restrict__ xo,
    bf16* __restrict__ z0, bf16* __restrict__ z1, bf16* __restrict__ Gin,
    int b0, int mreal, int z0rows, int rsB)
{
  const int bid = blockIdx.x;
  const int lb = bid >> 1, half = bid & 1, b = b0 + lb;
  const int tid = threadIdx.x, lane = tid & 63, w = tid >> 6;
  constexpr int KW = KS*32;
  const int mr = lane & 15;
  const int kq = (lane >> 4) << 3;

  bf16x8 af[MT][KS];
  const bf16* Cb = Cm + (size_t)b*(MT*16)*KW;
  #pragma unroll
  for (int m = 0; m < MT; ++m)
    #pragma unroll
    for (int ks = 0; ks < KS; ++ks)
      af[m][ks] = *(const bf16x8*)&Cb[(size_t)(m*16 + mr)*KW + ks*32 + kq];

  const int hb = half*384 + w*96 + mr;
  #pragma unroll 1
  for (int nt = 0; nt < 6; ++nt) {
    const int h = hb + nt*16;
    bf16x8 bfr[KS];
    #pragma unroll
    for (int ks = 0; ks < KS; ++ks) {
      union { unsigned short us[8]; bf16x8 v; } tmp;
      #pragma unroll
      for (int i = 0; i < 8; ++i) {
        int k = ks*32 + kq + i;
        if constexpr (CVT) {
          bool isl = (k < S_D);
          int kc = k - S_D; if (kc > C_D-1) kc = C_D-1;
          float fv = isl ? s0[((size_t)b*S_D + k)*768 + h]
                         : s1[((size_t)b*C_D + kc)*768 + h];
          bf16 hv = __float2bfloat16(fv);
          tmp.us[i] = *(unsigned short*)&hv;
          if constexpr (WG) {
            if (k < S_D + C_D) {
              size_t grow = isl ? ((size_t)lb*S_D + k)
                                : ((size_t)rsB + (size_t)lb*C_D + (k - S_D));
              ((unsigned short*)Gin)[grow*1536 + 768 + h] = tmp.us[i];
            }
          }
        } else {
          int kc = k; if (kc > S_D-1) kc = S_D-1;
          tmp.us[i] = ((const unsigned short*)xo)[((size_t)lb*S_D + kc)*768 + h];
        }
      }
      bfr[ks] = tmp.v;
    }
    #pragma unroll
    for (int m = 0; m < MT; ++m) {
      f32x4 acc = {};
      #pragma unroll
      for (int ks = 0; ks < KS; ++ks)
        acc = __builtin_amdgcn_mfma_f32_16x16x32_bf16(af[m][ks], bfr[ks], acc, 0, 0, 0);
      const int rb = m*16 + ((lane >> 4) << 2);
      #pragma unroll
      for (int r = 0; r < 4; ++r) {
        int mrow = rb + r;
        if (mrow < mreal) {
          bf16 ov = __float2bfloat16(acc[r]);
          bf16* dst = (mrow < z0rows)
            ? z0 + ((size_t)lb*z0rows + mrow)*768
            : z1 + ((size_t)lb*32 + (mrow - z0rows))*768;
          dst[h] = ov;
        }
      }
    }
  }
}

// ------------------------------------------------------------------
// MFMA GEMM: C[M x 768] = A[M x K] @ Bt[768 x K]^T. 128x128 tile, BK=64.
// T2 both-sides XOR swizzle + T1 bijective XCD swizzle + 2-phase LDS
// double-buffer prefetch. A dual-source: [0,SK) from A0, [SK,K) from A1.
// EPI 0: proj -> G left half = bf16(v + bias[col])
// EPI 1: gate -> Xo bf16; for rows>=rsB also G2 right half (new cls x)
// EPI 2: gate -> out f32 (cls rows; skip c==0)
// ------------------------------------------------------------------
template<int K, int EPI, int LDA0, int LDA1, int SK>
__global__ __launch_bounds__(256) void gemm_k(
    const bf16* __restrict__ A0, const bf16* __restrict__ A1,
    const bf16* __restrict__ Bt, bf16* __restrict__ G,
    bf16* __restrict__ G2, bf16* __restrict__ Xo, float* __restrict__ out,
    const float* __restrict__ bias, const float* __restrict__ bg,
    int b0, int rsB)
{
  __shared__ __align__(16) bf16 As[2][128*64];
  __shared__ __align__(16) bf16 Bs[2][128*64];
  const int tid  = threadIdx.x;
  const int lane = tid & 63;
  const int wave = tid >> 6;
  const int wm = wave >> 1, wn = wave & 1;

  // T1: bijective XCD-chunked swizzle (m204)
  const int nwg = gridDim.x;
  const int q = nwg >> 3, r = nwg & 7;
  const int xcd = blockIdx.x & 7, idx = blockIdx.x >> 3;
  const int wg = (xcd < r ? xcd*(q+1) : r*(q+1) + (xcd-r)*q) + idx;
  const int bm = wg / 6, bn = wg % 6;

  // T2 write side: pre-swizzled global source slot, linear LDS dest.
  const int swz = (((tid & 7) ^ ((tid >> 3) & 7))) << 3;   // elements
  const bf16* Ag0 = A0 + (size_t)(bm*128 + (tid>>3))*LDA0 + swz;
  const bf16* Ag1 = A1 + (size_t)(bm*128 + (tid>>3))*LDA1 + swz;
  const bf16* Bg  = Bt + (size_t)(bn*128 + (tid>>3))*K    + swz;
  const int ldsw = (wave*8)*64;

  f32x4 acc[4][4] = {};
  const int NT = K/64;

  auto stage = [&](int buf, int kt) {
    #pragma unroll
    for (int p = 0; p < 4; ++p) {
      const bf16* asrc = (kt < SK) ? (Ag0 + (size_t)(p*32)*LDA0 + kt)
                                   : (Ag1 + (size_t)(p*32)*LDA1 + (kt - SK));
      __builtin_amdgcn_global_load_lds(
        (const __attribute__((address_space(1))) void*)asrc,
        (__attribute__((address_space(3))) void*)(&As[buf][ldsw + p*32*64]), 16, 0, 0);
      __builtin_amdgcn_global_load_lds(
        (const __attribute__((address_space(1))) void*)(Bg + (size_t)(p*32)*K + kt),
        (__attribute__((address_space(3))) void*)(&Bs[buf][ldsw + p*32*64]), 16, 0, 0);
    }
  };

  stage(0, 0);
  __syncthreads();
  int cur = 0;
  #pragma unroll 1
  for (int t = 0; t < NT; ++t) {
    if (t + 1 < NT) stage(cur ^ 1, (t + 1)*64);   // prefetch flies under MFMA
    const bf16* Asb = As[cur];
    const bf16* Bsb = Bs[cur];
    #pragma unroll
    for (int ks = 0; ks < 64; ks += 32) {
      bf16x8 afv[4], bfv[4];
      const int sa = ((((ks >> 3) + (lane >> 4)) ^ (lane & 7))) << 3;
      #pragma unroll
      for (int i = 0; i < 4; ++i) {
        int m = wm*64 + i*16 + (lane & 15);
        afv[i] = *(const bf16x8*)&Asb[m*64 + sa];
        int n = wn*64 + i*16 + (lane & 15);
        bfv[i] = *(const bf16x8*)&Bsb[n*64 + sa];
      }
      #pragma unroll
      for (int i = 0; i < 4; ++i)
        #pragma unroll
        for (int j = 0; j < 4; ++j)
          acc[i][j] = __builtin_amdgcn_mfma_f32_16x16x32_bf16(afv[i], bfv[j], acc[i][j], 0, 0, 0);
    }
    __syncthreads();   // vmcnt(0)+barrier after compute: prefetch has landed
    cur ^= 1;
  }

  const int rbase = bm*128 + wm*64 + ((lane>>4)<<2);
  const int cbase = bn*128 + wn*64 + (lane & 15);
  #pragma unroll
  for (int i = 0; i < 4; ++i) {
    #pragma unroll
    for (int j = 0; j < 4; ++j) {
      const int col = cbase + j*16;
      #pragma unroll
      for (int r2 = 0; r2 < 4; ++r2) {
        const int row = rbase + i*16 + r2;
        float v = acc[i][j][r2];
        if constexpr (EPI == 0) {
          G[(size_t)row*1536 + col] = __float2bfloat16(v + bias[col]);
        } else if constexpr (EPI == 1) {
          v += bg[col];
          float g = 1.f/(1.f + __expf(-v));
          float u = __bfloat162float(G[(size_t)row*1536 + col]);
          float x = __bfloat162float(G[(size_t)row*1536 + 768 + col]);
          bf16 nv = __float2bfloat16(fmaxf(u, 0.f)*g + x*(1.f - g));
          Xo[(size_t)row*H_D + col] = nv;
          if (row >= rsB)
            G2[((size_t)(row - rsB))*1536 + 768 + col] = nv;
        } else { // EPI == 2: final cls gate -> out
          v += bg[col];
          float g = 1.f/(1.f + __expf(-v));
          float u = __bfloat162float(G[(size_t)row*1536 + col]);
          int bb = row >> 4, c = row & 15;
          if (c >= 1) {
            float x = __bfloat162float(Xo[(size_t)row*H_D + col]);
            out[((size_t)(b0 + bb)*15 + (c - 1))*H_D + col] =
                fmaxf(u, 0.f)*g + x*(1.f - g);
          }
        }
      }
    }
  }
}

// ------------------------------------------------------------------
extern "C" void kernel_launch(void* const* d_in, const int* in_sizes, int n_in,
                              void* d_out, int out_size, void* d_ws, size_t ws_size,
                              hipStream_t stream)
{
  const float* slots  = (const float*)d_in[0];
  const float* cls    = (const float*)d_in[1];
  const float* a_cur  = (const float*)d_in[2];
  const float* a_slot = (const float*)d_in[3];
  const float* a_last = (const float*)d_in[4];
  const float* a_dom  = (const float*)d_in[5];
  const float* W_r    = (const float*)d_in[6];
  const float* b_r    = (const float*)d_in[7];
  const float* W_s    = (const float*)d_in[8];
  const float* b_s    = (const float*)d_in[9];
  const float* W_g    = (const float*)d_in[10];
  const float* b_g    = (const float*)d_in[11];
  float* out = (float*)d_out;

  char* base = (char*)d_ws;
  size_t off = 0;
  auto alloc = [&](size_t bytes) -> void* {
    void* r = base + off;
    off = (off + bytes + 255) & ~(size_t)255;
    return r;
  };

  bf16* Wcat   = (bf16*)alloc((size_t)768*3840*2);
  bf16* Wg     = (bf16*)alloc((size_t)768*1536*2);
  bf16* Wcat2  = (bf16*)alloc((size_t)768*2304*2);
  bf16* Cmat   = (bf16*)alloc((size_t)512*160*64*2);
  bf16* Cmat2  = (bf16*)alloc((size_t)512*32*32*2);
  float* bslot = (float*)alloc(768*4);
  float* bcls  = (float*)alloc(768*4);
  size_t fixedOff = off;

  // per-batch: Gin [46x1536] + Xo [46x768] + Zs [120x768] + Zc [32x768], bf16
  const size_t perBatch = (size_t)46*1536*2 + (size_t)46*768*2
                        + (size_t)120*768*2 + (size_t)32*768*2;
  int chunkB = 512;
  while (chunkB > 64 && fixedOff + perBatch*(size_t)chunkB + 65536 > ws_size) chunkB >>= 1;

  const int rows_s = chunkB * S_D;
  const int rows_c = chunkB * C_D;
  const int rows_a = chunkB * (S_D + C_D);
  bf16* Gin = (bf16*)alloc((size_t)rows_a*1536*2);
  bf16* Xo  = (bf16*)alloc((size_t)rows_a*768*2);
  bf16* Zs  = (bf16*)alloc((size_t)chunkB*120*768*2);
  bf16* Zc  = (bf16*)alloc((size_t)chunkB*32*768*2);
  bf16* GinC = Gin + (size_t)rows_s*1536;
  bf16* XoC  = Xo  + (size_t)rows_s*768;
  bf16* GinC2 = Zs;   // alias: Zs is dead once the slot proj has run

  {
    int tot = 768*3840 + 768*1536 + 768*2304 + 768;
    prep_weights_k<<<(tot+255)/256, 256, 0, stream>>>(W_r, b_r, W_s, b_s, W_g,
                                                      Wcat, Wg, Wcat2, bslot, bcls);
  }
  prep_cmat_k<<<512, 64, 0, stream>>>(a_cur, a_slot, a_last, a_dom, Cmat, Cmat2);

  for (int b0 = 0; b0 < 512; b0 += chunkB) {
    // ---- layer 1 ----
    // aggregation GEMM: Zs (120 rows/b), Zc (32 rows/b), + Gin right halves
    aggmm_k<10,2,1,1><<<chunkB*2, 256, 0, stream>>>(
        Cmat, slots, cls, nullptr, Zs, Zc, Gin, b0, 152, 120, rows_s);
    // slot proj: A = [x | Zs], K=3840 -> Gin_s left (u + bslot)
    gemm_k<3840, 0, 1536, 3072, 768><<<(rows_s/128)*6, 256, 0, stream>>>(
        Gin + 768, Zs, Wcat, Gin, nullptr, Xo, out, bslot, b_g, b0, 0);
    // cls proj: A = [x | Zc], K=2304 -> Gin_c left (u + bcls)
    gemm_k<2304, 0, 1536, 1536, 768><<<(rows_c/128)*6, 256, 0, stream>>>(
        GinC + 768, Zc, Wcat2, GinC, nullptr, XoC, out, bcls, b_g, b0, 0);
    // gate (all rows): A = Gin = [u | x] -> Xo; cls rows also -> GinC2 right
    gemm_k<1536, 1, 1536, 1536, 1536><<<(rows_a/128)*6, 256, 0, stream>>>(
        Gin, Gin, Wg, Gin, GinC2, Xo, out, bslot, b_g, b0, rows_s);
    // ---- layer 2 (cls rows only) ----
    aggmm_k<2,1,0,0><<<chunkB*2, 256, 0, stream>>>(
        Cmat2, nullptr, nullptr, Xo, Zc, Zc, nullptr, b0, 32, 32, 0);
    gemm_k<2304, 0, 1536, 1536, 768><<<(rows_c/128)*6, 256, 0, stream>>>(
        GinC2 + 768, Zc, Wcat2, GinC2, nullptr, XoC, out, bcls, b_g, b0, 0);
    // final gate -> out
    gemm_k<1536, 2, 1536, 1536, 1536><<<(rows_c/128)*6, 256, 0, stream>>>(
        GinC2, GinC2, Wg, GinC2, nullptr, XoC, out, bcls, b_g, b0, 0);
  }
}

// Round 8
// 541.705 us; speedup vs baseline: 1.2382x; 1.2382x over previous
//
#include <hip/hip_runtime.h>
#include <hip/hip_bf16.h>
#include <cstdint>
#include <cstddef>

typedef __hip_bfloat16 bf16;
typedef __bf16 bf16x8 __attribute__((ext_vector_type(8)));
typedef float f32x4 __attribute__((ext_vector_type(4)));

#define S_D 30
#define C_D 16
#define H_D 768
#define EPS_F 1e-5f

// ------------------------------------------------------------------
// prep: bf16 transposed weight concats + folded biases.
// K-order PERMUTED to match packed aggregate layout:
// Wcat  [768n x 3840k]: k<768 -> W_s;  k=768+kk*4+seg -> W_r[seg][kk]
// Wcat2 [768n x 2304k]: k<768 -> W_s;  k=768+kk*2+seg -> W_r[seg?2:0][kk]
// Wg    [768n x 1536k]: W_g^T (unpermuted)
// ------------------------------------------------------------------
__global__ __launch_bounds__(256) void prep_weights_k(
    const float* __restrict__ W_r, const float* __restrict__ b_r,
    const float* __restrict__ W_s, const float* __restrict__ b_s,
    const float* __restrict__ W_g,
    bf16* __restrict__ Wcat, bf16* __restrict__ Wg, bf16* __restrict__ Wcat2,
    float* __restrict__ bslot, float* __restrict__ bcls)
{
  int id = blockIdx.x*256 + threadIdx.x;
  const int n1 = 768*3840, n2 = 768*1536, n3 = 768*2304;
  if (id < n1) {
    int n = id / 3840, k = id % 3840;
    float w;
    if (k < 768) w = W_s[k*768 + n];
    else { int j = k - 768, kk = j >> 2, seg = j & 3;
           w = W_r[((size_t)seg*768 + kk)*768 + n]; }
    Wcat[id] = __float2bfloat16(w);
  } else if (id < n1 + n2) {
    int j = id - n1; int n = j / 1536, k = j % 1536;
    Wg[j] = __float2bfloat16(W_g[(size_t)k*768 + n]);
  } else if (id < n1 + n2 + n3) {
    int j = id - n1 - n2; int n = j / 2304, k = j % 2304;
    float w;
    if (k < 768) w = W_s[k*768 + n];
    else { int jj = k - 768, kk = jj >> 1, seg = jj & 1;
           w = W_r[((size_t)(seg ? 2 : 0)*768 + kk)*768 + n]; }
    Wcat2[j] = __float2bfloat16(w);
  } else if (id < n1 + n2 + n3 + 768) {
    int n = id - n1 - n2 - n3;
    bslot[n] = b_s[n] + b_r[n] + b_r[768+n] + b_r[2*768+n] + b_r[3*768+n];
    bcls[n]  = b_s[n] + b_r[n] + b_r[2*768+n];
  }
}

// ------------------------------------------------------------------
// layer-1 aggregation + init. One block per batch, 256 threads, each
// thread owns 3 h-columns (h = tid, tid+256, tid+512). Normalized
// coefficient matrices staged in LDS (row-norm Lac/Las/Lal/Lad;
// col-norm transposed LacT/LalT, stride 32, zero-padded), read as
// float4 wave-uniform broadcasts. x in registers. Packed stores:
// Zs [row][kk*4+seg] (uint2), Zc [row][kk*2+seg] (uint).
// ------------------------------------------------------------------
__global__ __launch_bounds__(256) void agg1_k(
    const float* __restrict__ slots, const float* __restrict__ cls,
    const float* __restrict__ a_cur, const float* __restrict__ a_slot,
    const float* __restrict__ a_last, const float* __restrict__ a_dom,
    bf16* __restrict__ Gin, bf16* __restrict__ Zs, bf16* __restrict__ Zc,
    int b0, int rsBase)
{
  __shared__ float Lac[30*16], Lal[30*16];
  __shared__ float Las[30*32], Lad[30*32];
  __shared__ float LacT[16*32], LalT[16*32];
  __shared__ float ivr[4*32], ivc[2*16];
  const int lb = blockIdx.x, b = b0 + lb, tid = threadIdx.x;
  const float* ac  = a_cur  + (size_t)b*480;
  const float* as_ = a_slot + (size_t)b*900;
  const float* al  = a_last + (size_t)b*480;
  const float* ad  = a_dom  + (size_t)b*900;

  // phase 1: inverse sums
  if (tid < 30) {
    float s1=0, s3=0;
    for (int c=0;c<16;c++){ s1+=ac[tid*16+c]; s3+=al[tid*16+c]; }
    ivr[tid] = 1.f/(s1+EPS_F); ivr[32+tid] = 1.f/(s3+EPS_F);
    float s2=0, s4=0;
    for (int j=0;j<30;j++){ s2+=as_[tid*30+j]; s4+=ad[tid*30+j]; }
    ivr[64+tid] = 1.f/(s2+EPS_F); ivr[96+tid] = 1.f/(s4+EPS_F);
  } else if (tid < 46) {
    int c = tid - 30; float s1=0, s3=0;
    for (int s=0;s<30;s++){ s1+=ac[s*16+c]; s3+=al[s*16+c]; }
    ivc[c] = 1.f/(s1+EPS_F); ivc[16+c] = 1.f/(s3+EPS_F);
  }
  __syncthreads();
  // phase 2: fill normalized LDS tables
  for (int i = tid; i < 480; i += 256) {
    int s = i >> 4;
    Lac[i] = ac[i]*ivr[s];
    Lal[i] = al[i]*ivr[32+s];
  }
  for (int i = tid; i < 960; i += 256) {
    int s = i >> 5, j = i & 31;
    Las[i] = (j < 30) ? as_[s*30+j]*ivr[64+s] : 0.f;
    Lad[i] = (j < 30) ? ad[s*30+j]*ivr[96+s] : 0.f;
  }
  for (int i = tid; i < 512; i += 256) {
    int c = i >> 5, s = i & 31;
    LacT[i] = (s < 30) ? ac[s*16+c]*ivc[c]    : 0.f;
    LalT[i] = (s < 30) ? al[s*16+c]*ivc[16+c] : 0.f;
  }
  __syncthreads();

  // phase 3: load x (3 h-cols), init Gin right halves
  float xs[3][32], xc[3][16];
  #pragma unroll
  for (int j = 0; j < 3; ++j) {
    const int h = tid + j*256;
    #pragma unroll
    for (int s = 0; s < 30; ++s) xs[j][s] = slots[((size_t)b*30 + s)*768 + h];
    xs[j][30] = 0.f; xs[j][31] = 0.f;
    #pragma unroll
    for (int c = 0; c < 16; ++c) xc[j][c] = cls[((size_t)b*16 + c)*768 + h];
  }
  #pragma unroll
  for (int j = 0; j < 3; ++j) {
    const int h = tid + j*256;
    bf16* Gs = Gin + ((size_t)lb*30)*1536 + 768 + h;
    #pragma unroll
    for (int s = 0; s < 30; ++s) Gs[(size_t)s*1536] = __float2bfloat16(xs[j][s]);
    bf16* Gc = Gin + ((size_t)(rsBase + lb*16))*1536 + 768 + h;
    #pragma unroll
    for (int c = 0; c < 16; ++c) Gc[(size_t)c*1536] = __float2bfloat16(xc[j][c]);
  }

  // phase 4: slot rows
  #pragma unroll 2
  for (int s = 0; s < 30; ++s) {
    float a1[3] = {}, a2[3] = {}, a3[3] = {}, a4[3] = {};
    #pragma unroll
    for (int q = 0; q < 4; ++q) {
      float4 va = *(const float4*)&Lac[s*16 + q*4];
      float4 vl = *(const float4*)&Lal[s*16 + q*4];
      #pragma unroll
      for (int j = 0; j < 3; ++j) {
        a1[j] += va.x*xc[j][q*4] + va.y*xc[j][q*4+1] + va.z*xc[j][q*4+2] + va.w*xc[j][q*4+3];
        a3[j] += vl.x*xc[j][q*4] + vl.y*xc[j][q*4+1] + vl.z*xc[j][q*4+2] + vl.w*xc[j][q*4+3];
      }
    }
    #pragma unroll
    for (int q = 0; q < 8; ++q) {
      float4 vs = *(const float4*)&Las[s*32 + q*4];
      float4 vd = *(const float4*)&Lad[s*32 + q*4];
      #pragma unroll
      for (int j = 0; j < 3; ++j) {
        a2[j] += vs.x*xs[j][q*4] + vs.y*xs[j][q*4+1] + vs.z*xs[j][q*4+2] + vs.w*xs[j][q*4+3];
        a4[j] += vd.x*xs[j][q*4] + vd.y*xs[j][q*4+1] + vd.z*xs[j][q*4+2] + vd.w*xs[j][q*4+3];
      }
    }
    char* Zrow = (char*)Zs + (((size_t)lb*30 + s)*3072)*2;
    #pragma unroll
    for (int j = 0; j < 3; ++j) {
      const int h = tid + j*256;
      union { bf16 hv[4]; uint2 u; } p;
      p.hv[0] = __float2bfloat16(a1[j]);
      p.hv[1] = __float2bfloat16(a2[j]);
      p.hv[2] = __float2bfloat16(a3[j]);
      p.hv[3] = __float2bfloat16(a4[j]);
      *(uint2*)(Zrow + (size_t)h*8) = p.u;
    }
  }
  // phase 5: cls rows (col-normalized, transposed tables)
  #pragma unroll 2
  for (int c = 0; c < 16; ++c) {
    float a1[3] = {}, a3[3] = {};
    #pragma unroll
    for (int q = 0; q < 8; ++q) {
      float4 va = *(const float4*)&LacT[c*32 + q*4];
      float4 vl = *(const float4*)&LalT[c*32 + q*4];
      #pragma unroll
      for (int j = 0; j < 3; ++j) {
        a1[j] += va.x*xs[j][q*4] + va.y*xs[j][q*4+1] + va.z*xs[j][q*4+2] + va.w*xs[j][q*4+3];
        a3[j] += vl.x*xs[j][q*4] + vl.y*xs[j][q*4+1] + vl.z*xs[j][q*4+2] + vl.w*xs[j][q*4+3];
      }
    }
    char* Zrow = (char*)Zc + (((size_t)lb*16 + c)*1536)*2;
    #pragma unroll
    for (int j = 0; j < 3; ++j) {
      const int h = tid + j*256;
      union { bf16 hv[2]; unsigned u; } p;
      p.hv[0] = __float2bfloat16(a1[j]);
      p.hv[1] = __float2bfloat16(a3[j]);
      *(unsigned*)(Zrow + (size_t)h*4) = p.u;
    }
  }
}

// ------------------------------------------------------------------
// layer-2 aggregation (cls rows only) from layer-1 slot state Xo (bf16).
// Same LDS-staged transposed col-norm tables; packed Zc stores.
// (cls x right-half of GinC2 is written by the gate epilogue.)
// ------------------------------------------------------------------
__global__ __launch_bounds__(256) void agg2_k(
    const bf16* __restrict__ Xo,
    const float* __restrict__ a_cur, const float* __restrict__ a_last,
    bf16* __restrict__ Zc, int b0)
{
  __shared__ float LacT[16*32], LalT[16*32];
  __shared__ float ivc[2*16];
  const int lb = blockIdx.x, b = b0 + lb, tid = threadIdx.x;
  const float* ac = a_cur  + (size_t)b*480;
  const float* al = a_last + (size_t)b*480;
  if (tid < 16) {
    float s1=0, s3=0;
    for (int s=0;s<30;s++){ s1+=ac[s*16+tid]; s3+=al[s*16+tid]; }
    ivc[tid] = 1.f/(s1+EPS_F); ivc[16+tid] = 1.f/(s3+EPS_F);
  }
  __syncthreads();
  for (int i = tid; i < 512; i += 256) {
    int c = i >> 5, s = i & 31;
    LacT[i] = (s < 30) ? ac[s*16+c]*ivc[c]    : 0.f;
    LalT[i] = (s < 30) ? al[s*16+c]*ivc[16+c] : 0.f;
  }
  __syncthreads();

  float xs[3][32];
  #pragma unroll
  for (int j = 0; j < 3; ++j) {
    const int h = tid + j*256;
    #pragma unroll
    for (int s = 0; s < 30; ++s)
      xs[j][s] = __bfloat162float(Xo[((size_t)(lb*30 + s))*768 + h]);
    xs[j][30] = 0.f; xs[j][31] = 0.f;
  }
  #pragma unroll 2
  for (int c = 0; c < 16; ++c) {
    float a1[3] = {}, a3[3] = {};
    #pragma unroll
    for (int q = 0; q < 8; ++q) {
      float4 va = *(const float4*)&LacT[c*32 + q*4];
      float4 vl = *(const float4*)&LalT[c*32 + q*4];
      #pragma unroll
      for (int j = 0; j < 3; ++j) {
        a1[j] += va.x*xs[j][q*4] + va.y*xs[j][q*4+1] + va.z*xs[j][q*4+2] + va.w*xs[j][q*4+3];
        a3[j] += vl.x*xs[j][q*4] + vl.y*xs[j][q*4+1] + vl.z*xs[j][q*4+2] + vl.w*xs[j][q*4+3];
      }
    }
    char* Zrow = (char*)Zc + (((size_t)lb*16 + c)*1536)*2;
    #pragma unroll
    for (int j = 0; j < 3; ++j) {
      const int h = tid + j*256;
      union { bf16 hv[2]; unsigned u; } p;
      p.hv[0] = __float2bfloat16(a1[j]);
      p.hv[1] = __float2bfloat16(a3[j]);
      *(unsigned*)(Zrow + (size_t)h*4) = p.u;
    }
  }
}

// ------------------------------------------------------------------
// MFMA GEMM: C[M x 768] = A[M x K] @ Bt[768 x K]^T. 128x128 tile, BK=64.
// T2 both-sides XOR swizzle + T1 bijective XCD swizzle + 2-phase LDS
// double-buffer prefetch. A dual-source: [0,SK) from A0, [SK,K) from A1.
// EPI 0: proj -> G left half = bf16(v + bias[col])
// EPI 1: gate -> Xo bf16; rows>=rsB also G2 right half (new cls x)
// EPI 2: gate -> out f32 (cls rows; skip c==0)
// ------------------------------------------------------------------
template<int K, int EPI, int LDA0, int LDA1, int SK>
__global__ __launch_bounds__(256) void gemm_k(
    const bf16* __restrict__ A0, const bf16* __restrict__ A1,
    const bf16* __restrict__ Bt, bf16* __restrict__ G,
    bf16* __restrict__ G2, bf16* __restrict__ Xo, float* __restrict__ out,
    const float* __restrict__ bias, const float* __restrict__ bg,
    int b0, int rsB)
{
  __shared__ __align__(16) bf16 As[2][128*64];
  __shared__ __align__(16) bf16 Bs[2][128*64];
  const int tid  = threadIdx.x;
  const int lane = tid & 63;
  const int wave = tid >> 6;
  const int wm = wave >> 1, wn = wave & 1;

  // T1: bijective XCD-chunked swizzle (m204)
  const int nwg = gridDim.x;
  const int q = nwg >> 3, r = nwg & 7;
  const int xcd = blockIdx.x & 7, idx = blockIdx.x >> 3;
  const int wg = (xcd < r ? xcd*(q+1) : r*(q+1) + (xcd-r)*q) + idx;
  const int bm = wg / 6, bn = wg % 6;

  // T2 write side: pre-swizzled global source slot, linear LDS dest.
  const int swz = (((tid & 7) ^ ((tid >> 3) & 7))) << 3;   // elements
  const bf16* Ag0 = A0 + (size_t)(bm*128 + (tid>>3))*LDA0 + swz;
  const bf16* Ag1 = A1 + (size_t)(bm*128 + (tid>>3))*LDA1 + swz;
  const bf16* Bg  = Bt + (size_t)(bn*128 + (tid>>3))*K    + swz;
  const int ldsw = (wave*8)*64;

  f32x4 acc[4][4] = {};
  const int NT = K/64;

  auto stage = [&](int buf, int kt) {
    #pragma unroll
    for (int p = 0; p < 4; ++p) {
      const bf16* asrc = (kt < SK) ? (Ag0 + (size_t)(p*32)*LDA0 + kt)
                                   : (Ag1 + (size_t)(p*32)*LDA1 + (kt - SK));
      __builtin_amdgcn_global_load_lds(
        (const __attribute__((address_space(1))) void*)asrc,
        (__attribute__((address_space(3))) void*)(&As[buf][ldsw + p*32*64]), 16, 0, 0);
      __builtin_amdgcn_global_load_lds(
        (const __attribute__((address_space(1))) void*)(Bg + (size_t)(p*32)*K + kt),
        (__attribute__((address_space(3))) void*)(&Bs[buf][ldsw + p*32*64]), 16, 0, 0);
    }
  };

  stage(0, 0);
  __syncthreads();
  int cur = 0;
  #pragma unroll 1
  for (int t = 0; t < NT; ++t) {
    if (t + 1 < NT) stage(cur ^ 1, (t + 1)*64);   // prefetch flies under MFMA
    const bf16* Asb = As[cur];
    const bf16* Bsb = Bs[cur];
    #pragma unroll
    for (int ks = 0; ks < 64; ks += 32) {
      bf16x8 afv[4], bfv[4];
      const int sa = ((((ks >> 3) + (lane >> 4)) ^ (lane & 7))) << 3;
      #pragma unroll
      for (int i = 0; i < 4; ++i) {
        int m = wm*64 + i*16 + (lane & 15);
        afv[i] = *(const bf16x8*)&Asb[m*64 + sa];
        int n = wn*64 + i*16 + (lane & 15);
        bfv[i] = *(const bf16x8*)&Bsb[n*64 + sa];
      }
      #pragma unroll
      for (int i = 0; i < 4; ++i)
        #pragma unroll
        for (int j = 0; j < 4; ++j)
          acc[i][j] = __builtin_amdgcn_mfma_f32_16x16x32_bf16(afv[i], bfv[j], acc[i][j], 0, 0, 0);
    }
    __syncthreads();   // vmcnt(0)+barrier after compute: prefetch has landed
    cur ^= 1;
  }

  const int rbase = bm*128 + wm*64 + ((lane>>4)<<2);
  const int cbase = bn*128 + wn*64 + (lane & 15);
  #pragma unroll
  for (int i = 0; i < 4; ++i) {
    #pragma unroll
    for (int j = 0; j < 4; ++j) {
      const int col = cbase + j*16;
      #pragma unroll
      for (int r2 = 0; r2 < 4; ++r2) {
        const int row = rbase + i*16 + r2;
        float v = acc[i][j][r2];
        if constexpr (EPI == 0) {
          G[(size_t)row*1536 + col] = __float2bfloat16(v + bias[col]);
        } else if constexpr (EPI == 1) {
          v += bg[col];
          float g = 1.f/(1.f + __expf(-v));
          float u = __bfloat162float(G[(size_t)row*1536 + col]);
          float x = __bfloat162float(G[(size_t)row*1536 + 768 + col]);
          bf16 nv = __float2bfloat16(fmaxf(u, 0.f)*g + x*(1.f - g));
          Xo[(size_t)row*H_D + col] = nv;
          if (row >= rsB)
            G2[((size_t)(row - rsB))*1536 + 768 + col] = nv;
        } else { // EPI == 2: final cls gate -> out
          v += bg[col];
          float g = 1.f/(1.f + __expf(-v));
          float u = __bfloat162float(G[(size_t)row*1536 + col]);
          int bb = row >> 4, c = row & 15;
          if (c >= 1) {
            float x = __bfloat162float(Xo[(size_t)row*H_D + col]);
            out[((size_t)(b0 + bb)*15 + (c - 1))*H_D + col] =
                fmaxf(u, 0.f)*g + x*(1.f - g);
          }
        }
      }
    }
  }
}

// ------------------------------------------------------------------
extern "C" void kernel_launch(void* const* d_in, const int* in_sizes, int n_in,
                              void* d_out, int out_size, void* d_ws, size_t ws_size,
                              hipStream_t stream)
{
  const float* slots  = (const float*)d_in[0];
  const float* cls    = (const float*)d_in[1];
  const float* a_cur  = (const float*)d_in[2];
  const float* a_slot = (const float*)d_in[3];
  const float* a_last = (const float*)d_in[4];
  const float* a_dom  = (const float*)d_in[5];
  const float* W_r    = (const float*)d_in[6];
  const float* b_r    = (const float*)d_in[7];
  const float* W_s    = (const float*)d_in[8];
  const float* b_s    = (const float*)d_in[9];
  const float* W_g    = (const float*)d_in[10];
  const float* b_g    = (const float*)d_in[11];
  float* out = (float*)d_out;

  char* base = (char*)d_ws;
  size_t off = 0;
  auto alloc = [&](size_t bytes) -> void* {
    void* r = base + off;
    off = (off + bytes + 255) & ~(size_t)255;
    return r;
  };

  bf16* Wcat   = (bf16*)alloc((size_t)768*3840*2);
  bf16* Wg     = (bf16*)alloc((size_t)768*1536*2);
  bf16* Wcat2  = (bf16*)alloc((size_t)768*2304*2);
  float* bslot = (float*)alloc(768*4);
  float* bcls  = (float*)alloc(768*4);
  size_t fixedOff = off;

  // per-batch: Gin [46x1536] + Xo [46x768] + Zs [30x3072] + Zc [16x1536], bf16
  const size_t perBatch = (size_t)46*1536*2 + (size_t)46*768*2
                        + (size_t)30*3072*2 + (size_t)16*1536*2;
  int chunkB = 512;
  while (chunkB > 64 && fixedOff + perBatch*(size_t)chunkB + 65536 > ws_size) chunkB >>= 1;

  const int rows_s = chunkB * S_D;
  const int rows_c = chunkB * C_D;
  const int rows_a = chunkB * (S_D + C_D);
  bf16* Gin = (bf16*)alloc((size_t)rows_a*1536*2);
  bf16* Xo  = (bf16*)alloc((size_t)rows_a*768*2);
  bf16* Zs  = (bf16*)alloc((size_t)rows_s*3072*2);
  bf16* Zc  = (bf16*)alloc((size_t)rows_c*1536*2);
  bf16* GinC = Gin + (size_t)rows_s*1536;
  bf16* XoC  = Xo  + (size_t)rows_s*768;
  bf16* GinC2 = Zs;   // alias: Zs is dead once the slot proj has run

  {
    int tot = 768*3840 + 768*1536 + 768*2304 + 768;
    prep_weights_k<<<(tot+255)/256, 256, 0, stream>>>(W_r, b_r, W_s, b_s, W_g,
                                                      Wcat, Wg, Wcat2, bslot, bcls);
  }

  for (int b0 = 0; b0 < 512; b0 += chunkB) {
    // ---- layer 1 ----
    agg1_k<<<chunkB, 256, 0, stream>>>(slots, cls, a_cur, a_slot, a_last, a_dom,
                                       Gin, Zs, Zc, b0, rows_s);
    // slot proj: A = [x | Zs packed], K=3840 -> Gin_s left (u + bslot)
    gemm_k<3840, 0, 1536, 3072, 768><<<(rows_s/128)*6, 256, 0, stream>>>(
        Gin + 768, Zs, Wcat, Gin, nullptr, Xo, out, bslot, b_g, b0, 0);
    // cls proj: A = [x | Zc packed], K=2304 -> Gin_c left (u + bcls)
    gemm_k<2304, 0, 1536, 1536, 768><<<(rows_c/128)*6, 256, 0, stream>>>(
        GinC + 768, Zc, Wcat2, GinC, nullptr, XoC, out, bcls, b_g, b0, 0);
    // gate (all rows): A = Gin = [u | x] -> Xo; cls rows also -> GinC2 right
    gemm_k<1536, 1, 1536, 1536, 1536><<<(rows_a/128)*6, 256, 0, stream>>>(
        Gin, Gin, Wg, Gin, GinC2, Xo, out, bslot, b_g, b0, rows_s);
    // ---- layer 2 (cls rows only) ----
    agg2_k<<<chunkB, 256, 0, stream>>>(Xo, a_cur, a_last, Zc, b0);
    gemm_k<2304, 0, 1536, 1536, 768><<<(rows_c/128)*6, 256, 0, stream>>>(
        GinC2 + 768, Zc, Wcat2, GinC2, nullptr, XoC, out, bcls, b_g, b0, 0);
    // final gate -> out
    gemm_k<1536, 2, 1536, 1536, 1536><<<(rows_c/128)*6, 256, 0, stream>>>(
        GinC2, GinC2, Wg, GinC2, nullptr, XoC, out, bcls, b_g, b0, 0);
  }
}

// Round 9
// 539.045 us; speedup vs baseline: 1.2444x; 1.0049x over previous
//
#include <hip/hip_runtime.h>
#include <hip/hip_bf16.h>
#include <cstdint>
#include <cstddef>

typedef __hip_bfloat16 bf16;
typedef __bf16 bf16x8 __attribute__((ext_vector_type(8)));
typedef float f32x4 __attribute__((ext_vector_type(4)));

#define S_D 30
#define C_D 16
#define H_D 768
#define EPS_F 1e-5f

// ------------------------------------------------------------------
// prep: bf16 transposed weight concats + folded biases.
// K-order PERMUTED to match packed aggregate layout:
// Wcat  [768n x 3840k]: k<768 -> W_s;  k=768+kk*4+seg -> W_r[seg][kk]
// Wcat2 [768n x 2304k]: k<768 -> W_s;  k=768+kk*2+seg -> W_r[seg?2:0][kk]
// Wg    [768n x 1536k]: W_g^T (unpermuted)
// ------------------------------------------------------------------
__global__ __launch_bounds__(256) void prep_weights_k(
    const float* __restrict__ W_r, const float* __restrict__ b_r,
    const float* __restrict__ W_s, const float* __restrict__ b_s,
    const float* __restrict__ W_g,
    bf16* __restrict__ Wcat, bf16* __restrict__ Wg, bf16* __restrict__ Wcat2,
    float* __restrict__ bslot, float* __restrict__ bcls)
{
  int id = blockIdx.x*256 + threadIdx.x;
  const int n1 = 768*3840, n2 = 768*1536, n3 = 768*2304;
  if (id < n1) {
    int n = id / 3840, k = id % 3840;
    float w;
    if (k < 768) w = W_s[k*768 + n];
    else { int j = k - 768, kk = j >> 2, seg = j & 3;
           w = W_r[((size_t)seg*768 + kk)*768 + n]; }
    Wcat[id] = __float2bfloat16(w);
  } else if (id < n1 + n2) {
    int j = id - n1; int n = j / 1536, k = j % 1536;
    Wg[j] = __float2bfloat16(W_g[(size_t)k*768 + n]);
  } else if (id < n1 + n2 + n3) {
    int j = id - n1 - n2; int n = j / 2304, k = j % 2304;
    float w;
    if (k < 768) w = W_s[k*768 + n];
    else { int jj = k - 768, kk = jj >> 1, seg = jj & 1;
           w = W_r[((size_t)(seg ? 2 : 0)*768 + kk)*768 + n]; }
    Wcat2[j] = __float2bfloat16(w);
  } else if (id < n1 + n2 + n3 + 768) {
    int n = id - n1 - n2 - n3;
    bslot[n] = b_s[n] + b_r[n] + b_r[768+n] + b_r[2*768+n] + b_r[3*768+n];
    bcls[n]  = b_s[n] + b_r[n] + b_r[2*768+n];
  }
}

// ------------------------------------------------------------------
// layer-1 aggregation + init (unchanged from R8: LDS-staged normalized
// coef tables, 3 h-cols/thread, packed uint2/uint Z stores).
// ------------------------------------------------------------------
__global__ __launch_bounds__(256) void agg1_k(
    const float* __restrict__ slots, const float* __restrict__ cls,
    const float* __restrict__ a_cur, const float* __restrict__ a_slot,
    const float* __restrict__ a_last, const float* __restrict__ a_dom,
    bf16* __restrict__ Gin, bf16* __restrict__ Zs, bf16* __restrict__ Zc,
    int b0, int rsBase)
{
  __shared__ float Lac[30*16], Lal[30*16];
  __shared__ float Las[30*32], Lad[30*32];
  __shared__ float LacT[16*32], LalT[16*32];
  __shared__ float ivr[4*32], ivc[2*16];
  const int lb = blockIdx.x, b = b0 + lb, tid = threadIdx.x;
  const float* ac  = a_cur  + (size_t)b*480;
  const float* as_ = a_slot + (size_t)b*900;
  const float* al  = a_last + (size_t)b*480;
  const float* ad  = a_dom  + (size_t)b*900;

  if (tid < 30) {
    float s1=0, s3=0;
    for (int c=0;c<16;c++){ s1+=ac[tid*16+c]; s3+=al[tid*16+c]; }
    ivr[tid] = 1.f/(s1+EPS_F); ivr[32+tid] = 1.f/(s3+EPS_F);
    float s2=0, s4=0;
    for (int j=0;j<30;j++){ s2+=as_[tid*30+j]; s4+=ad[tid*30+j]; }
    ivr[64+tid] = 1.f/(s2+EPS_F); ivr[96+tid] = 1.f/(s4+EPS_F);
  } else if (tid < 46) {
    int c = tid - 30; float s1=0, s3=0;
    for (int s=0;s<30;s++){ s1+=ac[s*16+c]; s3+=al[s*16+c]; }
    ivc[c] = 1.f/(s1+EPS_F); ivc[16+c] = 1.f/(s3+EPS_F);
  }
  __syncthreads();
  for (int i = tid; i < 480; i += 256) {
    int s = i >> 4;
    Lac[i] = ac[i]*ivr[s];
    Lal[i] = al[i]*ivr[32+s];
  }
  for (int i = tid; i < 960; i += 256) {
    int s = i >> 5, j = i & 31;
    Las[i] = (j < 30) ? as_[s*30+j]*ivr[64+s] : 0.f;
    Lad[i] = (j < 30) ? ad[s*30+j]*ivr[96+s] : 0.f;
  }
  for (int i = tid; i < 512; i += 256) {
    int c = i >> 5, s = i & 31;
    LacT[i] = (s < 30) ? ac[s*16+c]*ivc[c]    : 0.f;
    LalT[i] = (s < 30) ? al[s*16+c]*ivc[16+c] : 0.f;
  }
  __syncthreads();

  float xs[3][32], xc[3][16];
  #pragma unroll
  for (int j = 0; j < 3; ++j) {
    const int h = tid + j*256;
    #pragma unroll
    for (int s = 0; s < 30; ++s) xs[j][s] = slots[((size_t)b*30 + s)*768 + h];
    xs[j][30] = 0.f; xs[j][31] = 0.f;
    #pragma unroll
    for (int c = 0; c < 16; ++c) xc[j][c] = cls[((size_t)b*16 + c)*768 + h];
  }
  #pragma unroll
  for (int j = 0; j < 3; ++j) {
    const int h = tid + j*256;
    bf16* Gs = Gin + ((size_t)lb*30)*1536 + 768 + h;
    #pragma unroll
    for (int s = 0; s < 30; ++s) Gs[(size_t)s*1536] = __float2bfloat16(xs[j][s]);
    bf16* Gc = Gin + ((size_t)(rsBase + lb*16))*1536 + 768 + h;
    #pragma unroll
    for (int c = 0; c < 16; ++c) Gc[(size_t)c*1536] = __float2bfloat16(xc[j][c]);
  }

  #pragma unroll 2
  for (int s = 0; s < 30; ++s) {
    float a1[3] = {}, a2[3] = {}, a3[3] = {}, a4[3] = {};
    #pragma unroll
    for (int q = 0; q < 4; ++q) {
      float4 va = *(const float4*)&Lac[s*16 + q*4];
      float4 vl = *(const float4*)&Lal[s*16 + q*4];
      #pragma unroll
      for (int j = 0; j < 3; ++j) {
        a1[j] += va.x*xc[j][q*4] + va.y*xc[j][q*4+1] + va.z*xc[j][q*4+2] + va.w*xc[j][q*4+3];
        a3[j] += vl.x*xc[j][q*4] + vl.y*xc[j][q*4+1] + vl.z*xc[j][q*4+2] + vl.w*xc[j][q*4+3];
      }
    }
    #pragma unroll
    for (int q = 0; q < 8; ++q) {
      float4 vs = *(const float4*)&Las[s*32 + q*4];
      float4 vd = *(const float4*)&Lad[s*32 + q*4];
      #pragma unroll
      for (int j = 0; j < 3; ++j) {
        a2[j] += vs.x*xs[j][q*4] + vs.y*xs[j][q*4+1] + vs.z*xs[j][q*4+2] + vs.w*xs[j][q*4+3];
        a4[j] += vd.x*xs[j][q*4] + vd.y*xs[j][q*4+1] + vd.z*xs[j][q*4+2] + vd.w*xs[j][q*4+3];
      }
    }
    char* Zrow = (char*)Zs + (((size_t)lb*30 + s)*3072)*2;
    #pragma unroll
    for (int j = 0; j < 3; ++j) {
      const int h = tid + j*256;
      union { bf16 hv[4]; uint2 u; } p;
      p.hv[0] = __float2bfloat16(a1[j]);
      p.hv[1] = __float2bfloat16(a2[j]);
      p.hv[2] = __float2bfloat16(a3[j]);
      p.hv[3] = __float2bfloat16(a4[j]);
      *(uint2*)(Zrow + (size_t)h*8) = p.u;
    }
  }
  #pragma unroll 2
  for (int c = 0; c < 16; ++c) {
    float a1[3] = {}, a3[3] = {};
    #pragma unroll
    for (int q = 0; q < 8; ++q) {
      float4 va = *(const float4*)&LacT[c*32 + q*4];
      float4 vl = *(const float4*)&LalT[c*32 + q*4];
      #pragma unroll
      for (int j = 0; j < 3; ++j) {
        a1[j] += va.x*xs[j][q*4] + va.y*xs[j][q*4+1] + va.z*xs[j][q*4+2] + va.w*xs[j][q*4+3];
        a3[j] += vl.x*xs[j][q*4] + vl.y*xs[j][q*4+1] + vl.z*xs[j][q*4+2] + vl.w*xs[j][q*4+3];
      }
    }
    char* Zrow = (char*)Zc + (((size_t)lb*16 + c)*1536)*2;
    #pragma unroll
    for (int j = 0; j < 3; ++j) {
      const int h = tid + j*256;
      union { bf16 hv[2]; unsigned u; } p;
      p.hv[0] = __float2bfloat16(a1[j]);
      p.hv[1] = __float2bfloat16(a3[j]);
      *(unsigned*)(Zrow + (size_t)h*4) = p.u;
    }
  }
}

// ------------------------------------------------------------------
// layer-2 aggregation (cls rows only) from layer-1 slot state Xo (bf16).
// ------------------------------------------------------------------
__global__ __launch_bounds__(256) void agg2_k(
    const bf16* __restrict__ Xo,
    const float* __restrict__ a_cur, const float* __restrict__ a_last,
    bf16* __restrict__ Zc, int b0)
{
  __shared__ float LacT[16*32], LalT[16*32];
  __shared__ float ivc[2*16];
  const int lb = blockIdx.x, b = b0 + lb, tid = threadIdx.x;
  const float* ac = a_cur  + (size_t)b*480;
  const float* al = a_last + (size_t)b*480;
  if (tid < 16) {
    float s1=0, s3=0;
    for (int s=0;s<30;s++){ s1+=ac[s*16+tid]; s3+=al[s*16+tid]; }
    ivc[tid] = 1.f/(s1+EPS_F); ivc[16+tid] = 1.f/(s3+EPS_F);
  }
  __syncthreads();
  for (int i = tid; i < 512; i += 256) {
    int c = i >> 5, s = i & 31;
    LacT[i] = (s < 30) ? ac[s*16+c]*ivc[c]    : 0.f;
    LalT[i] = (s < 30) ? al[s*16+c]*ivc[16+c] : 0.f;
  }
  __syncthreads();

  float xs[3][32];
  #pragma unroll
  for (int j = 0; j < 3; ++j) {
    const int h = tid + j*256;
    #pragma unroll
    for (int s = 0; s < 30; ++s)
      xs[j][s] = __bfloat162float(Xo[((size_t)(lb*30 + s))*768 + h]);
    xs[j][30] = 0.f; xs[j][31] = 0.f;
  }
  #pragma unroll 2
  for (int c = 0; c < 16; ++c) {
    float a1[3] = {}, a3[3] = {};
    #pragma unroll
    for (int q = 0; q < 8; ++q) {
      float4 va = *(const float4*)&LacT[c*32 + q*4];
      float4 vl = *(const float4*)&LalT[c*32 + q*4];
      #pragma unroll
      for (int j = 0; j < 3; ++j) {
        a1[j] += va.x*xs[j][q*4] + va.y*xs[j][q*4+1] + va.z*xs[j][q*4+2] + va.w*xs[j][q*4+3];
        a3[j] += vl.x*xs[j][q*4] + vl.y*xs[j][q*4+1] + vl.z*xs[j][q*4+2] + vl.w*xs[j][q*4+3];
      }
    }
    char* Zrow = (char*)Zc + (((size_t)lb*16 + c)*1536)*2;
    #pragma unroll
    for (int j = 0; j < 3; ++j) {
      const int h = tid + j*256;
      union { bf16 hv[2]; unsigned u; } p;
      p.hv[0] = __float2bfloat16(a1[j]);
      p.hv[1] = __float2bfloat16(a3[j]);
      *(unsigned*)(Zrow + (size_t)h*4) = p.u;
    }
  }
}

// ------------------------------------------------------------------
// GEMM body (device fn): C[128 x 128 tile] of A[M x K] @ Bt[768 x K]^T.
// T2 both-sides XOR swizzle; DBUF=true: 2-phase prefetch (for small
// grids, 64 KB LDS); DBUF=false: single 32 KB buffer (for >=1k-block
// grids -> 4 blocks/CU co-residency hides the barrier drain, m97/m114).
// EPI 0: proj -> G left half = bf16(v + bias[col])
// EPI 1: gate -> Xo bf16; rows>=rsB also G2 right half (new cls x)
// EPI 2: gate -> out f32 (cls rows; skip c==0)
// ------------------------------------------------------------------
template<int K, int EPI, int LDA0, int LDA1, int SK, bool DBUF>
__device__ __forceinline__ void gemm_body(
    bf16* __restrict__ As, bf16* __restrict__ Bs, int wg,
    const bf16* __restrict__ A0, const bf16* __restrict__ A1,
    const bf16* __restrict__ Bt, bf16* __restrict__ G,
    bf16* __restrict__ G2, bf16* __restrict__ Xo, float* __restrict__ out,
    const float* __restrict__ bias, const float* __restrict__ bg,
    int b0, int rsB)
{
  const int tid  = threadIdx.x;
  const int lane = tid & 63;
  const int wave = tid >> 6;
  const int wm = wave >> 1, wn = wave & 1;
  const int bm = wg / 6, bn = wg % 6;

  const int swz = (((tid & 7) ^ ((tid >> 3) & 7))) << 3;   // elements
  const bf16* Ag0 = A0 + (size_t)(bm*128 + (tid>>3))*LDA0 + swz;
  const bf16* Ag1 = A1 + (size_t)(bm*128 + (tid>>3))*LDA1 + swz;
  const bf16* Bg  = Bt + (size_t)(bn*128 + (tid>>3))*K    + swz;
  const int ldsw = (wave*8)*64;

  f32x4 acc[4][4] = {};
  const int NT = K/64;

  auto stage = [&](int buf, int kt) {
    #pragma unroll
    for (int p = 0; p < 4; ++p) {
      const bf16* asrc = (kt < SK) ? (Ag0 + (size_t)(p*32)*LDA0 + kt)
                                   : (Ag1 + (size_t)(p*32)*LDA1 + (kt - SK));
      __builtin_amdgcn_global_load_lds(
        (const __attribute__((address_space(1))) void*)asrc,
        (__attribute__((address_space(3))) void*)(&As[buf*8192 + ldsw + p*32*64]), 16, 0, 0);
      __builtin_amdgcn_global_load_lds(
        (const __attribute__((address_space(1))) void*)(Bg + (size_t)(p*32)*K + kt),
        (__attribute__((address_space(3))) void*)(&Bs[buf*8192 + ldsw + p*32*64]), 16, 0, 0);
    }
  };

  auto compute = [&](int buf) {
    const bf16* Asb = As + buf*8192;
    const bf16* Bsb = Bs + buf*8192;
    #pragma unroll
    for (int ks = 0; ks < 64; ks += 32) {
      bf16x8 afv[4], bfv[4];
      const int sa = ((((ks >> 3) + (lane >> 4)) ^ (lane & 7))) << 3;
      #pragma unroll
      for (int i = 0; i < 4; ++i) {
        int m = wm*64 + i*16 + (lane & 15);
        afv[i] = *(const bf16x8*)&Asb[m*64 + sa];
        int n = wn*64 + i*16 + (lane & 15);
        bfv[i] = *(const bf16x8*)&Bsb[n*64 + sa];
      }
      #pragma unroll
      for (int i = 0; i < 4; ++i)
        #pragma unroll
        for (int j = 0; j < 4; ++j)
          acc[i][j] = __builtin_amdgcn_mfma_f32_16x16x32_bf16(afv[i], bfv[j], acc[i][j], 0, 0, 0);
    }
  };

  if constexpr (DBUF) {
    stage(0, 0);
    __syncthreads();
    int cur = 0;
    #pragma unroll 1
    for (int t = 0; t < NT; ++t) {
      if (t + 1 < NT) stage(cur ^ 1, (t + 1)*64);  // prefetch under MFMA
      compute(cur);
      __syncthreads();
      cur ^= 1;
    }
  } else {
    #pragma unroll 1
    for (int t = 0; t < NT; ++t) {
      stage(0, t*64);
      __syncthreads();     // loads landed
      compute(0);
      __syncthreads();     // reads done before next overwrite
    }
  }

  const int rbase = bm*128 + wm*64 + ((lane>>4)<<2);
  const int cbase = bn*128 + wn*64 + (lane & 15);
  #pragma unroll
  for (int i = 0; i < 4; ++i) {
    #pragma unroll
    for (int j = 0; j < 4; ++j) {
      const int col = cbase + j*16;
      #pragma unroll
      for (int r2 = 0; r2 < 4; ++r2) {
        const int row = rbase + i*16 + r2;
        float v = acc[i][j][r2];
        if constexpr (EPI == 0) {
          G[(size_t)row*1536 + col] = __float2bfloat16(v + bias[col]);
        } else if constexpr (EPI == 1) {
          v += bg[col];
          float g = 1.f/(1.f + __expf(-v));
          float u = __bfloat162float(G[(size_t)row*1536 + col]);
          float x = __bfloat162float(G[(size_t)row*1536 + 768 + col]);
          bf16 nv = __float2bfloat16(fmaxf(u, 0.f)*g + x*(1.f - g));
          Xo[(size_t)row*H_D + col] = nv;
          if (row >= rsB)
            G2[((size_t)(row - rsB))*1536 + 768 + col] = nv;
        } else { // EPI == 2
          v += bg[col];
          float g = 1.f/(1.f + __expf(-v));
          float u = __bfloat162float(G[(size_t)row*1536 + col]);
          int bb = row >> 4, c = row & 15;
          if (c >= 1) {
            float x = __bfloat162float(Xo[(size_t)row*H_D + col]);
            out[((size_t)(b0 + bb)*15 + (c - 1))*H_D + col] =
                fmaxf(u, 0.f)*g + x*(1.f - g);
          }
        }
      }
    }
  }
}

// T1 bijective XCD-chunked swizzle (m204)
__device__ __forceinline__ int xcd_swizzle(int bid, int nwg) {
  const int q = nwg >> 3, r = nwg & 7;
  const int xcd = bid & 7, idx = bid >> 3;
  return (xcd < r ? xcd*(q+1) : r*(q+1) + (xcd-r)*q) + idx;
}

// Standalone GEMM kernel
template<int K, int EPI, int LDA0, int LDA1, int SK, bool DBUF>
__global__ __launch_bounds__(256) void gemm_k(
    const bf16* __restrict__ A0, const bf16* __restrict__ A1,
    const bf16* __restrict__ Bt, bf16* __restrict__ G,
    bf16* __restrict__ G2, bf16* __restrict__ Xo, float* __restrict__ out,
    const float* __restrict__ bias, const float* __restrict__ bg,
    int b0, int rsB)
{
  __shared__ __align__(16) bf16 As[(DBUF ? 2 : 1)*128*64];
  __shared__ __align__(16) bf16 Bs[(DBUF ? 2 : 1)*128*64];
  int wg = xcd_swizzle(blockIdx.x, gridDim.x);
  gemm_body<K, EPI, LDA0, LDA1, SK, DBUF>(As, Bs, wg, A0, A1, Bt, G, G2, Xo,
                                          out, bias, bg, b0, rsB);
}

// Merged layer-1 projection: blocks [0,nS) slot proj (K=3840),
// [nS, nS+nC) cls proj (K=2304). Single-buffer LDS, one launch.
__global__ __launch_bounds__(256) void proj1_k(
    const bf16* __restrict__ GinSx, const bf16* __restrict__ Zs,
    const bf16* __restrict__ Wcat,  bf16* __restrict__ GS,
    const bf16* __restrict__ GinCx, const bf16* __restrict__ Zc,
    const bf16* __restrict__ Wcat2, bf16* __restrict__ GC,
    const float* __restrict__ bslot, const float* __restrict__ bcls, int nS)
{
  __shared__ __align__(16) bf16 As[128*64];
  __shared__ __align__(16) bf16 Bs[128*64];
  int wg = xcd_swizzle(blockIdx.x, gridDim.x);
  if (wg < nS) {
    gemm_body<3840, 0, 1536, 3072, 768, false>(As, Bs, wg, GinSx, Zs, Wcat, GS,
        nullptr, nullptr, nullptr, bslot, nullptr, 0, 0);
  } else {
    gemm_body<2304, 0, 1536, 1536, 768, false>(As, Bs, wg - nS, GinCx, Zc, Wcat2, GC,
        nullptr, nullptr, nullptr, bcls, nullptr, 0, 0);
  }
}

// ------------------------------------------------------------------
extern "C" void kernel_launch(void* const* d_in, const int* in_sizes, int n_in,
                              void* d_out, int out_size, void* d_ws, size_t ws_size,
                              hipStream_t stream)
{
  const float* slots  = (const float*)d_in[0];
  const float* cls    = (const float*)d_in[1];
  const float* a_cur  = (const float*)d_in[2];
  const float* a_slot = (const float*)d_in[3];
  const float* a_last = (const float*)d_in[4];
  const float* a_dom  = (const float*)d_in[5];
  const float* W_r    = (const float*)d_in[6];
  const float* b_r    = (const float*)d_in[7];
  const float* W_s    = (const float*)d_in[8];
  const float* b_s    = (const float*)d_in[9];
  const float* W_g    = (const float*)d_in[10];
  const float* b_g    = (const float*)d_in[11];
  float* out = (float*)d_out;

  char* base = (char*)d_ws;
  size_t off = 0;
  auto alloc = [&](size_t bytes) -> void* {
    void* r = base + off;
    off = (off + bytes + 255) & ~(size_t)255;
    return r;
  };

  bf16* Wcat   = (bf16*)alloc((size_t)768*3840*2);
  bf16* Wg     = (bf16*)alloc((size_t)768*1536*2);
  bf16* Wcat2  = (bf16*)alloc((size_t)768*2304*2);
  float* bslot = (float*)alloc(768*4);
  float* bcls  = (float*)alloc(768*4);
  size_t fixedOff = off;

  // per-batch: Gin [46x1536] + Xo [46x768] + Zs [30x3072] + Zc [16x1536], bf16
  const size_t perBatch = (size_t)46*1536*2 + (size_t)46*768*2
                        + (size_t)30*3072*2 + (size_t)16*1536*2;
  int chunkB = 512;
  while (chunkB > 64 && fixedOff + perBatch*(size_t)chunkB + 65536 > ws_size) chunkB >>= 1;

  const int rows_s = chunkB * S_D;
  const int rows_c = chunkB * C_D;
  const int rows_a = chunkB * (S_D + C_D);
  bf16* Gin = (bf16*)alloc((size_t)rows_a*1536*2);
  bf16* Xo  = (bf16*)alloc((size_t)rows_a*768*2);
  bf16* Zs  = (bf16*)alloc((size_t)rows_s*3072*2);
  bf16* Zc  = (bf16*)alloc((size_t)rows_c*1536*2);
  bf16* GinC = Gin + (size_t)rows_s*1536;
  bf16* XoC  = Xo  + (size_t)rows_s*768;
  bf16* GinC2 = Zs;   // alias: Zs is dead once the slot proj has run

  {
    int tot = 768*3840 + 768*1536 + 768*2304 + 768;
    prep_weights_k<<<(tot+255)/256, 256, 0, stream>>>(W_r, b_r, W_s, b_s, W_g,
                                                      Wcat, Wg, Wcat2, bslot, bcls);
  }

  for (int b0 = 0; b0 < 512; b0 += chunkB) {
    const int nS = (rows_s/128)*6, nC = (rows_c/128)*6;
    // ---- layer 1 ----
    agg1_k<<<chunkB, 256, 0, stream>>>(slots, cls, a_cur, a_slot, a_last, a_dom,
                                       Gin, Zs, Zc, b0, rows_s);
    // merged slot+cls proj (1104 blocks, 1buf -> 4 blocks/CU)
    proj1_k<<<nS + nC, 256, 0, stream>>>(Gin + 768, Zs, Wcat, Gin,
                                         GinC + 768, Zc, Wcat2, GinC,
                                         bslot, bcls, nS);
    // gate (all rows): A = Gin = [u | x] -> Xo; cls rows also -> GinC2 right
    gemm_k<1536, 1, 1536, 1536, 1536, false><<<(rows_a/128)*6, 256, 0, stream>>>(
        Gin, Gin, Wg, Gin, GinC2, Xo, out, bslot, b_g, b0, rows_s);
    // ---- layer 2 (cls rows only; small grids -> dbuf prefetch) ----
    agg2_k<<<chunkB, 256, 0, stream>>>(Xo, a_cur, a_last, Zc, b0);
    gemm_k<2304, 0, 1536, 1536, 768, true><<<nC, 256, 0, stream>>>(
        GinC2 + 768, Zc, Wcat2, GinC2, nullptr, XoC, out, bcls, b_g, b0, 0);
    // final gate -> out
    gemm_k<1536, 2, 1536, 1536, 1536, true><<<nC, 256, 0, stream>>>(
        GinC2, GinC2, Wg, GinC2, nullptr, XoC, out, bcls, b_g, b0, 0);
  }
}

// Round 10
// 538.042 us; speedup vs baseline: 1.2467x; 1.0019x over previous
//
#include <hip/hip_runtime.h>
#include <hip/hip_bf16.h>
#include <cstdint>
#include <cstddef>

typedef __hip_bfloat16 bf16;
typedef __bf16 bf16x8 __attribute__((ext_vector_type(8)));
typedef float f32x4 __attribute__((ext_vector_type(4)));

#define S_D 30
#define C_D 16
#define H_D 768
#define EPS_F 1e-5f

// ------------------------------------------------------------------
// prep: bf16 transposed weight concats + folded biases.
// K-order PERMUTED to match packed aggregate layout:
// Wcat  [768n x 3840k]: k<768 -> W_s;  k=768+kk*4+seg -> W_r[seg][kk]
// Wcat2 [768n x 2304k]: k<768 -> W_s;  k=768+kk*2+seg -> W_r[seg?2:0][kk]
// Wg    [768n x 1536k]: W_g^T (unpermuted)
// ------------------------------------------------------------------
__global__ __launch_bounds__(256) void prep_weights_k(
    const float* __restrict__ W_r, const float* __restrict__ b_r,
    const float* __restrict__ W_s, const float* __restrict__ b_s,
    const float* __restrict__ W_g,
    bf16* __restrict__ Wcat, bf16* __restrict__ Wg, bf16* __restrict__ Wcat2,
    float* __restrict__ bslot, float* __restrict__ bcls)
{
  int id = blockIdx.x*256 + threadIdx.x;
  const int n1 = 768*3840, n2 = 768*1536, n3 = 768*2304;
  if (id < n1) {
    int n = id / 3840, k = id % 3840;
    float w;
    if (k < 768) w = W_s[k*768 + n];
    else { int j = k - 768, kk = j >> 2, seg = j & 3;
           w = W_r[((size_t)seg*768 + kk)*768 + n]; }
    Wcat[id] = __float2bfloat16(w);
  } else if (id < n1 + n2) {
    int j = id - n1; int n = j / 1536, k = j % 1536;
    Wg[j] = __float2bfloat16(W_g[(size_t)k*768 + n]);
  } else if (id < n1 + n2 + n3) {
    int j = id - n1 - n2; int n = j / 2304, k = j % 2304;
    float w;
    if (k < 768) w = W_s[k*768 + n];
    else { int jj = k - 768, kk = jj >> 1, seg = jj & 1;
           w = W_r[((size_t)(seg ? 2 : 0)*768 + kk)*768 + n]; }
    Wcat2[j] = __float2bfloat16(w);
  } else if (id < n1 + n2 + n3 + 768) {
    int n = id - n1 - n2 - n3;
    bslot[n] = b_s[n] + b_r[n] + b_r[768+n] + b_r[2*768+n] + b_r[3*768+n];
    bcls[n]  = b_s[n] + b_r[n] + b_r[2*768+n];
  }
}

// ------------------------------------------------------------------
// layer-1 aggregation + init (R8 structure: LDS-staged normalized coef
// tables, 3 h-cols/thread, packed uint2/uint Z stores).
// ------------------------------------------------------------------
__global__ __launch_bounds__(256) void agg1_k(
    const float* __restrict__ slots, const float* __restrict__ cls,
    const float* __restrict__ a_cur, const float* __restrict__ a_slot,
    const float* __restrict__ a_last, const float* __restrict__ a_dom,
    bf16* __restrict__ Gin, bf16* __restrict__ Zs, bf16* __restrict__ Zc,
    int b0, int rsBase)
{
  __shared__ float Lac[30*16], Lal[30*16];
  __shared__ float Las[30*32], Lad[30*32];
  __shared__ float LacT[16*32], LalT[16*32];
  __shared__ float ivr[4*32], ivc[2*16];
  const int lb = blockIdx.x, b = b0 + lb, tid = threadIdx.x;
  const float* ac  = a_cur  + (size_t)b*480;
  const float* as_ = a_slot + (size_t)b*900;
  const float* al  = a_last + (size_t)b*480;
  const float* ad  = a_dom  + (size_t)b*900;

  if (tid < 30) {
    float s1=0, s3=0;
    for (int c=0;c<16;c++){ s1+=ac[tid*16+c]; s3+=al[tid*16+c]; }
    ivr[tid] = 1.f/(s1+EPS_F); ivr[32+tid] = 1.f/(s3+EPS_F);
    float s2=0, s4=0;
    for (int j=0;j<30;j++){ s2+=as_[tid*30+j]; s4+=ad[tid*30+j]; }
    ivr[64+tid] = 1.f/(s2+EPS_F); ivr[96+tid] = 1.f/(s4+EPS_F);
  } else if (tid < 46) {
    int c = tid - 30; float s1=0, s3=0;
    for (int s=0;s<30;s++){ s1+=ac[s*16+c]; s3+=al[s*16+c]; }
    ivc[c] = 1.f/(s1+EPS_F); ivc[16+c] = 1.f/(s3+EPS_F);
  }
  __syncthreads();
  for (int i = tid; i < 480; i += 256) {
    int s = i >> 4;
    Lac[i] = ac[i]*ivr[s];
    Lal[i] = al[i]*ivr[32+s];
  }
  for (int i = tid; i < 960; i += 256) {
    int s = i >> 5, j = i & 31;
    Las[i] = (j < 30) ? as_[s*30+j]*ivr[64+s] : 0.f;
    Lad[i] = (j < 30) ? ad[s*30+j]*ivr[96+s] : 0.f;
  }
  for (int i = tid; i < 512; i += 256) {
    int c = i >> 5, s = i & 31;
    LacT[i] = (s < 30) ? ac[s*16+c]*ivc[c]    : 0.f;
    LalT[i] = (s < 30) ? al[s*16+c]*ivc[16+c] : 0.f;
  }
  __syncthreads();

  float xs[3][32], xc[3][16];
  #pragma unroll
  for (int j = 0; j < 3; ++j) {
    const int h = tid + j*256;
    #pragma unroll
    for (int s = 0; s < 30; ++s) xs[j][s] = slots[((size_t)b*30 + s)*768 + h];
    xs[j][30] = 0.f; xs[j][31] = 0.f;
    #pragma unroll
    for (int c = 0; c < 16; ++c) xc[j][c] = cls[((size_t)b*16 + c)*768 + h];
  }
  #pragma unroll
  for (int j = 0; j < 3; ++j) {
    const int h = tid + j*256;
    bf16* Gs = Gin + ((size_t)lb*30)*1536 + 768 + h;
    #pragma unroll
    for (int s = 0; s < 30; ++s) Gs[(size_t)s*1536] = __float2bfloat16(xs[j][s]);
    bf16* Gc = Gin + ((size_t)(rsBase + lb*16))*1536 + 768 + h;
    #pragma unroll
    for (int c = 0; c < 16; ++c) Gc[(size_t)c*1536] = __float2bfloat16(xc[j][c]);
  }

  #pragma unroll 2
  for (int s = 0; s < 30; ++s) {
    float a1[3] = {}, a2[3] = {}, a3[3] = {}, a4[3] = {};
    #pragma unroll
    for (int q = 0; q < 4; ++q) {
      float4 va = *(const float4*)&Lac[s*16 + q*4];
      float4 vl = *(const float4*)&Lal[s*16 + q*4];
      #pragma unroll
      for (int j = 0; j < 3; ++j) {
        a1[j] += va.x*xc[j][q*4] + va.y*xc[j][q*4+1] + va.z*xc[j][q*4+2] + va.w*xc[j][q*4+3];
        a3[j] += vl.x*xc[j][q*4] + vl.y*xc[j][q*4+1] + vl.z*xc[j][q*4+2] + vl.w*xc[j][q*4+3];
      }
    }
    #pragma unroll
    for (int q = 0; q < 8; ++q) {
      float4 vs = *(const float4*)&Las[s*32 + q*4];
      float4 vd = *(const float4*)&Lad[s*32 + q*4];
      #pragma unroll
      for (int j = 0; j < 3; ++j) {
        a2[j] += vs.x*xs[j][q*4] + vs.y*xs[j][q*4+1] + vs.z*xs[j][q*4+2] + vs.w*xs[j][q*4+3];
        a4[j] += vd.x*xs[j][q*4] + vd.y*xs[j][q*4+1] + vd.z*xs[j][q*4+2] + vd.w*xs[j][q*4+3];
      }
    }
    char* Zrow = (char*)Zs + (((size_t)lb*30 + s)*3072)*2;
    #pragma unroll
    for (int j = 0; j < 3; ++j) {
      const int h = tid + j*256;
      union { bf16 hv[4]; uint2 u; } p;
      p.hv[0] = __float2bfloat16(a1[j]);
      p.hv[1] = __float2bfloat16(a2[j]);
      p.hv[2] = __float2bfloat16(a3[j]);
      p.hv[3] = __float2bfloat16(a4[j]);
      *(uint2*)(Zrow + (size_t)h*8) = p.u;
    }
  }
  #pragma unroll 2
  for (int c = 0; c < 16; ++c) {
    float a1[3] = {}, a3[3] = {};
    #pragma unroll
    for (int q = 0; q < 8; ++q) {
      float4 va = *(const float4*)&LacT[c*32 + q*4];
      float4 vl = *(const float4*)&LalT[c*32 + q*4];
      #pragma unroll
      for (int j = 0; j < 3; ++j) {
        a1[j] += va.x*xs[j][q*4] + va.y*xs[j][q*4+1] + va.z*xs[j][q*4+2] + va.w*xs[j][q*4+3];
        a3[j] += vl.x*xs[j][q*4] + vl.y*xs[j][q*4+1] + vl.z*xs[j][q*4+2] + vl.w*xs[j][q*4+3];
      }
    }
    char* Zrow = (char*)Zc + (((size_t)lb*16 + c)*1536)*2;
    #pragma unroll
    for (int j = 0; j < 3; ++j) {
      const int h = tid + j*256;
      union { bf16 hv[2]; unsigned u; } p;
      p.hv[0] = __float2bfloat16(a1[j]);
      p.hv[1] = __float2bfloat16(a3[j]);
      *(unsigned*)(Zrow + (size_t)h*4) = p.u;
    }
  }
}

// ------------------------------------------------------------------
// layer-2 aggregation (cls rows only) from layer-1 slot state Xo (bf16).
// ------------------------------------------------------------------
__global__ __launch_bounds__(256) void agg2_k(
    const bf16* __restrict__ Xo,
    const float* __restrict__ a_cur, const float* __restrict__ a_last,
    bf16* __restrict__ Zc, int b0)
{
  __shared__ float LacT[16*32], LalT[16*32];
  __shared__ float ivc[2*16];
  const int lb = blockIdx.x, b = b0 + lb, tid = threadIdx.x;
  const float* ac = a_cur  + (size_t)b*480;
  const float* al = a_last + (size_t)b*480;
  if (tid < 16) {
    float s1=0, s3=0;
    for (int s=0;s<30;s++){ s1+=ac[s*16+tid]; s3+=al[s*16+tid]; }
    ivc[tid] = 1.f/(s1+EPS_F); ivc[16+tid] = 1.f/(s3+EPS_F);
  }
  __syncthreads();
  for (int i = tid; i < 512; i += 256) {
    int c = i >> 5, s = i & 31;
    LacT[i] = (s < 30) ? ac[s*16+c]*ivc[c]    : 0.f;
    LalT[i] = (s < 30) ? al[s*16+c]*ivc[16+c] : 0.f;
  }
  __syncthreads();

  float xs[3][32];
  #pragma unroll
  for (int j = 0; j < 3; ++j) {
    const int h = tid + j*256;
    #pragma unroll
    for (int s = 0; s < 30; ++s)
      xs[j][s] = __bfloat162float(Xo[((size_t)(lb*30 + s))*768 + h]);
    xs[j][30] = 0.f; xs[j][31] = 0.f;
  }
  #pragma unroll 2
  for (int c = 0; c < 16; ++c) {
    float a1[3] = {}, a3[3] = {};
    #pragma unroll
    for (int q = 0; q < 8; ++q) {
      float4 va = *(const float4*)&LacT[c*32 + q*4];
      float4 vl = *(const float4*)&LalT[c*32 + q*4];
      #pragma unroll
      for (int j = 0; j < 3; ++j) {
        a1[j] += va.x*xs[j][q*4] + va.y*xs[j][q*4+1] + va.z*xs[j][q*4+2] + va.w*xs[j][q*4+3];
        a3[j] += vl.x*xs[j][q*4] + vl.y*xs[j][q*4+1] + vl.z*xs[j][q*4+2] + vl.w*xs[j][q*4+3];
      }
    }
    char* Zrow = (char*)Zc + (((size_t)lb*16 + c)*1536)*2;
    #pragma unroll
    for (int j = 0; j < 3; ++j) {
      const int h = tid + j*256;
      union { bf16 hv[2]; unsigned u; } p;
      p.hv[0] = __float2bfloat16(a1[j]);
      p.hv[1] = __float2bfloat16(a3[j]);
      *(unsigned*)(Zrow + (size_t)h*4) = p.u;
    }
  }
}

// ------------------------------------------------------------------
// GEMM body (device fn): one 128x128 tile of A[M x K] @ Bt[768 x K]^T.
// T2 both-sides XOR swizzle; DBUF=true: 2-phase prefetch (small grids);
// DBUF=false: single 32 KB buffer (big grids -> 4+ blocks/CU
// co-residency hides the barrier drain, m97/m114).
// EPI 0: proj -> G left half = bf16(v + bias[col])
// EPI 1: gate -> Xo bf16; rows>=rsB also G2 right half (new cls x)
// EPI 2: gate -> out f32 (cls rows; skip c==0)
// ------------------------------------------------------------------
template<int K, int EPI, int LDA0, int LDA1, int SK, bool DBUF>
__device__ __forceinline__ void gemm_body(
    bf16* __restrict__ As, bf16* __restrict__ Bs, int wg,
    const bf16* __restrict__ A0, const bf16* __restrict__ A1,
    const bf16* __restrict__ Bt, bf16* __restrict__ G,
    bf16* __restrict__ G2, bf16* __restrict__ Xo, float* __restrict__ out,
    const float* __restrict__ bias, const float* __restrict__ bg,
    int b0, int rsB)
{
  const int tid  = threadIdx.x;
  const int lane = tid & 63;
  const int wave = tid >> 6;
  const int wm = wave >> 1, wn = wave & 1;
  const int bm = wg / 6, bn = wg % 6;

  const int swz = (((tid & 7) ^ ((tid >> 3) & 7))) << 3;   // elements
  const bf16* Ag0 = A0 + (size_t)(bm*128 + (tid>>3))*LDA0 + swz;
  const bf16* Ag1 = A1 + (size_t)(bm*128 + (tid>>3))*LDA1 + swz;
  const bf16* Bg  = Bt + (size_t)(bn*128 + (tid>>3))*K    + swz;
  const int ldsw = (wave*8)*64;

  f32x4 acc[4][4] = {};
  const int NT = K/64;

  auto stage = [&](int buf, int kt) {
    #pragma unroll
    for (int p = 0; p < 4; ++p) {
      const bf16* asrc = (kt < SK) ? (Ag0 + (size_t)(p*32)*LDA0 + kt)
                                   : (Ag1 + (size_t)(p*32)*LDA1 + (kt - SK));
      __builtin_amdgcn_global_load_lds(
        (const __attribute__((address_space(1))) void*)asrc,
        (__attribute__((address_space(3))) void*)(&As[buf*8192 + ldsw + p*32*64]), 16, 0, 0);
      __builtin_amdgcn_global_load_lds(
        (const __attribute__((address_space(1))) void*)(Bg + (size_t)(p*32)*K + kt),
        (__attribute__((address_space(3))) void*)(&Bs[buf*8192 + ldsw + p*32*64]), 16, 0, 0);
    }
  };

  auto compute = [&](int buf) {
    const bf16* Asb = As + buf*8192;
    const bf16* Bsb = Bs + buf*8192;
    #pragma unroll
    for (int ks = 0; ks < 64; ks += 32) {
      bf16x8 afv[4], bfv[4];
      const int sa = ((((ks >> 3) + (lane >> 4)) ^ (lane & 7))) << 3;
      #pragma unroll
      for (int i = 0; i < 4; ++i) {
        int m = wm*64 + i*16 + (lane & 15);
        afv[i] = *(const bf16x8*)&Asb[m*64 + sa];
        int n = wn*64 + i*16 + (lane & 15);
        bfv[i] = *(const bf16x8*)&Bsb[n*64 + sa];
      }
      #pragma unroll
      for (int i = 0; i < 4; ++i)
        #pragma unroll
        for (int j = 0; j < 4; ++j)
          acc[i][j] = __builtin_amdgcn_mfma_f32_16x16x32_bf16(afv[i], bfv[j], acc[i][j], 0, 0, 0);
    }
  };

  if constexpr (DBUF) {
    stage(0, 0);
    __syncthreads();
    int cur = 0;
    #pragma unroll 1
    for (int t = 0; t < NT; ++t) {
      if (t + 1 < NT) stage(cur ^ 1, (t + 1)*64);  // prefetch under MFMA
      compute(cur);
      __syncthreads();
      cur ^= 1;
    }
  } else {
    #pragma unroll 1
    for (int t = 0; t < NT; ++t) {
      stage(0, t*64);
      __syncthreads();     // loads landed
      compute(0);
      __syncthreads();     // reads done before next overwrite
    }
  }

  const int rbase = bm*128 + wm*64 + ((lane>>4)<<2);
  const int cbase = bn*128 + wn*64 + (lane & 15);
  #pragma unroll
  for (int i = 0; i < 4; ++i) {
    #pragma unroll
    for (int j = 0; j < 4; ++j) {
      const int col = cbase + j*16;
      #pragma unroll
      for (int r2 = 0; r2 < 4; ++r2) {
        const int row = rbase + i*16 + r2;
        float v = acc[i][j][r2];
        if constexpr (EPI == 0) {
          G[(size_t)row*1536 + col] = __float2bfloat16(v + bias[col]);
        } else if constexpr (EPI == 1) {
          v += bg[col];
          float g = 1.f/(1.f + __expf(-v));
          float u = __bfloat162float(G[(size_t)row*1536 + col]);
          float x = __bfloat162float(G[(size_t)row*1536 + 768 + col]);
          bf16 nv = __float2bfloat16(fmaxf(u, 0.f)*g + x*(1.f - g));
          Xo[(size_t)row*H_D + col] = nv;
          if (row >= rsB)
            G2[((size_t)(row - rsB))*1536 + 768 + col] = nv;
        } else { // EPI == 2
          v += bg[col];
          float g = 1.f/(1.f + __expf(-v));
          float u = __bfloat162float(G[(size_t)row*1536 + col]);
          int bb = row >> 4, c = row & 15;
          if (c >= 1) {
            float x = __bfloat162float(Xo[(size_t)row*H_D + col]);
            out[((size_t)(b0 + bb)*15 + (c - 1))*H_D + col] =
                fmaxf(u, 0.f)*g + x*(1.f - g);
          }
        }
      }
    }
  }
}

// T1 bijective XCD-chunked swizzle (m204)
__device__ __forceinline__ int xcd_swizzle(int bid, int nwg) {
  const int q = nwg >> 3, r = nwg & 7;
  const int xcd = bid & 7, idx = bid >> 3;
  return (xcd < r ? xcd*(q+1) : r*(q+1) + (xcd-r)*q) + idx;
}

// Standalone GEMM kernel
template<int K, int EPI, int LDA0, int LDA1, int SK, bool DBUF>
__global__ __launch_bounds__(256) void gemm_k(
    const bf16* __restrict__ A0, const bf16* __restrict__ A1,
    const bf16* __restrict__ Bt, bf16* __restrict__ G,
    bf16* __restrict__ G2, bf16* __restrict__ Xo, float* __restrict__ out,
    const float* __restrict__ bias, const float* __restrict__ bg,
    int b0, int rsB)
{
  __shared__ __align__(16) bf16 As[(DBUF ? 2 : 1)*128*64];
  __shared__ __align__(16) bf16 Bs[(DBUF ? 2 : 1)*128*64];
  int wg = xcd_swizzle(blockIdx.x, gridDim.x);
  gemm_body<K, EPI, LDA0, LDA1, SK, DBUF>(As, Bs, wg, A0, A1, Bt, G, G2, Xo,
                                          out, bias, bg, b0, rsB);
}

// Merged layer-1 projection: blocks [0,nS) slot proj (K=3840),
// [nS, nS+nC) cls proj (K=2304). Single-buffer LDS, one launch.
__global__ __launch_bounds__(256) void proj1_k(
    const bf16* __restrict__ GinSx, const bf16* __restrict__ Zs,
    const bf16* __restrict__ Wcat,  bf16* __restrict__ GS,
    const bf16* __restrict__ GinCx, const bf16* __restrict__ Zc,
    const bf16* __restrict__ Wcat2, bf16* __restrict__ GC,
    const float* __restrict__ bslot, const float* __restrict__ bcls, int nS)
{
  __shared__ __align__(16) bf16 As[128*64];
  __shared__ __align__(16) bf16 Bs[128*64];
  int wg = xcd_swizzle(blockIdx.x, gridDim.x);
  if (wg < nS) {
    gemm_body<3840, 0, 1536, 3072, 768, false>(As, Bs, wg, GinSx, Zs, Wcat, GS,
        nullptr, nullptr, nullptr, bslot, nullptr, 0, 0);
  } else {
    gemm_body<2304, 0, 1536, 1536, 768, false>(As, Bs, wg - nS, GinCx, Zc, Wcat2, GC,
        nullptr, nullptr, nullptr, bcls, nullptr, 0, 0);
  }
}

// ------------------------------------------------------------------
extern "C" void kernel_launch(void* const* d_in, const int* in_sizes, int n_in,
                              void* d_out, int out_size, void* d_ws, size_t ws_size,
                              hipStream_t stream)
{
  const float* slots  = (const float*)d_in[0];
  const float* cls    = (const float*)d_in[1];
  const float* a_cur  = (const float*)d_in[2];
  const float* a_slot = (const float*)d_in[3];
  const float* a_last = (const float*)d_in[4];
  const float* a_dom  = (const float*)d_in[5];
  const float* W_r    = (const float*)d_in[6];
  const float* b_r    = (const float*)d_in[7];
  const float* W_s    = (const float*)d_in[8];
  const float* b_s    = (const float*)d_in[9];
  const float* W_g    = (const float*)d_in[10];
  const float* b_g    = (const float*)d_in[11];
  float* out = (float*)d_out;

  char* base = (char*)d_ws;
  size_t off = 0;
  auto alloc = [&](size_t bytes) -> void* {
    void* r = base + off;
    off = (off + bytes + 255) & ~(size_t)255;
    return r;
  };

  bf16* Wcat   = (bf16*)alloc((size_t)768*3840*2);
  bf16* Wg     = (bf16*)alloc((size_t)768*1536*2);
  bf16* Wcat2  = (bf16*)alloc((size_t)768*2304*2);
  float* bslot = (float*)alloc(768*4);
  float* bcls  = (float*)alloc(768*4);
  size_t fixedOff = off;

  // per-batch: Gin [46x1536] + Zs [30x3072] + Zc [16x1536], bf16.
  // Xo and GinC2 ALIAS into Zs (dead after proj1):
  //   Xo    = Zs base            (rows_a x 768)
  //   GinC2 = Zs + rows_a*768    (rows_c x 1536)
  //   needs 46*768 + 16*1536 = 59904 elems/b  <=  30*3072 = 92160  OK
  const size_t perBatch = (size_t)46*1536*2 + (size_t)30*3072*2 + (size_t)16*1536*2;
  int chunkB = 512;
  while (chunkB > 64 && fixedOff + perBatch*(size_t)chunkB + 65536 > ws_size) chunkB >>= 1;

  const int rows_s = chunkB * S_D;
  const int rows_c = chunkB * C_D;
  const int rows_a = chunkB * (S_D + C_D);
  bf16* Gin = (bf16*)alloc((size_t)rows_a*1536*2);
  bf16* Zs  = (bf16*)alloc((size_t)rows_s*3072*2);
  bf16* Zc  = (bf16*)alloc((size_t)rows_c*1536*2);
  bf16* GinC = Gin + (size_t)rows_s*1536;
  bf16* Xo    = Zs;                                   // alias (Zs dead post-proj1)
  bf16* XoC   = Xo + (size_t)rows_s*768;
  bf16* GinC2 = Zs + (size_t)rows_a*768;              // alias, disjoint from Xo

  {
    int tot = 768*3840 + 768*1536 + 768*2304 + 768;
    prep_weights_k<<<(tot+255)/256, 256, 0, stream>>>(W_r, b_r, W_s, b_s, W_g,
                                                      Wcat, Wg, Wcat2, bslot, bcls);
  }

  for (int b0 = 0; b0 < 512; b0 += chunkB) {
    const int nS = (rows_s/128)*6, nC = (rows_c/128)*6;
    // ---- layer 1 ----
    agg1_k<<<chunkB, 256, 0, stream>>>(slots, cls, a_cur, a_slot, a_last, a_dom,
                                       Gin, Zs, Zc, b0, rows_s);
    // merged slot+cls proj (single-buffer; chunkB=512 -> 1104 blocks)
    proj1_k<<<nS + nC, 256, 0, stream>>>(Gin + 768, Zs, Wcat, Gin,
                                         GinC + 768, Zc, Wcat2, GinC,
                                         bslot, bcls, nS);
    // gate (all rows): A = Gin = [u | x] -> Xo; cls rows also -> GinC2 right
    gemm_k<1536, 1, 1536, 1536, 1536, false><<<(rows_a/128)*6, 256, 0, stream>>>(
        Gin, Gin, Wg, Gin, GinC2, Xo, out, bslot, b_g, b0, rows_s);
    // ---- layer 2 (cls rows only; small grids -> dbuf prefetch) ----
    agg2_k<<<chunkB, 256, 0, stream>>>(Xo, a_cur, a_last, Zc, b0);
    gemm_k<2304, 0, 1536, 1536, 768, true><<<nC, 256, 0, stream>>>(
        GinC2 + 768, Zc, Wcat2, GinC2, nullptr, XoC, out, bcls, b_g, b0, 0);
    // final gate -> out
    gemm_k<1536, 2, 1536, 1536, 1536, true><<<nC, 256, 0, stream>>>(
        GinC2, GinC2, Wg, GinC2, nullptr, XoC, out, bcls, b_g, b0, 0);
  }
}

// Round 11
// 504.821 us; speedup vs baseline: 1.3287x; 1.0658x over previous
//
#include <hip/hip_runtime.h>
#include <hip/hip_bf16.h>
#include <cstdint>
#include <cstddef>

typedef __hip_bfloat16 bf16;
typedef __bf16 bf16x8 __attribute__((ext_vector_type(8)));
typedef float f32x4 __attribute__((ext_vector_type(4)));

#define S_D 30
#define C_D 16
#define H_D 768
#define EPS_F 1e-5f

// ------------------------------------------------------------------
// prep: bf16 transposed weight concats + folded biases.
// K-order PERMUTED to match packed aggregate layout:
// Wcat  [768n x 3840k]: k<768 -> W_s;  k=768+kk*4+seg -> W_r[seg][kk]
// Wcat2 [768n x 2304k]: k<768 -> W_s;  k=768+kk*2+seg -> W_r[seg?2:0][kk]
// Wg    [768n x 1536k]: W_g^T (unpermuted)
// ------------------------------------------------------------------
__global__ __launch_bounds__(256) void prep_weights_k(
    const float* __restrict__ W_r, const float* __restrict__ b_r,
    const float* __restrict__ W_s, const float* __restrict__ b_s,
    const float* __restrict__ W_g,
    bf16* __restrict__ Wcat, bf16* __restrict__ Wg, bf16* __restrict__ Wcat2,
    float* __restrict__ bslot, float* __restrict__ bcls)
{
  int id = blockIdx.x*256 + threadIdx.x;
  const int n1 = 768*3840, n2 = 768*1536, n3 = 768*2304;
  if (id < n1) {
    int n = id / 3840, k = id % 3840;
    float w;
    if (k < 768) w = W_s[k*768 + n];
    else { int j = k - 768, kk = j >> 2, seg = j & 3;
           w = W_r[((size_t)seg*768 + kk)*768 + n]; }
    Wcat[id] = __float2bfloat16(w);
  } else if (id < n1 + n2) {
    int j = id - n1; int n = j / 1536, k = j % 1536;
    Wg[j] = __float2bfloat16(W_g[(size_t)k*768 + n]);
  } else if (id < n1 + n2 + n3) {
    int j = id - n1 - n2; int n = j / 2304, k = j % 2304;
    float w;
    if (k < 768) w = W_s[k*768 + n];
    else { int jj = k - 768, kk = jj >> 1, seg = jj & 1;
           w = W_r[((size_t)(seg ? 2 : 0)*768 + kk)*768 + n]; }
    Wcat2[j] = __float2bfloat16(w);
  } else if (id < n1 + n2 + n3 + 768) {
    int n = id - n1 - n2 - n3;
    bslot[n] = b_s[n] + b_r[n] + b_r[768+n] + b_r[2*768+n] + b_r[3*768+n];
    bcls[n]  = b_s[n] + b_r[n] + b_r[2*768+n];
  }
}

// ------------------------------------------------------------------
// layer-1 aggregation + init (R8 structure: LDS-staged normalized coef
// tables, 3 h-cols/thread, packed uint2/uint Z stores).
// ------------------------------------------------------------------
__global__ __launch_bounds__(256) void agg1_k(
    const float* __restrict__ slots, const float* __restrict__ cls,
    const float* __restrict__ a_cur, const float* __restrict__ a_slot,
    const float* __restrict__ a_last, const float* __restrict__ a_dom,
    bf16* __restrict__ Gin, bf16* __restrict__ Zs, bf16* __restrict__ Zc,
    int b0, int rsBase)
{
  __shared__ float Lac[30*16], Lal[30*16];
  __shared__ float Las[30*32], Lad[30*32];
  __shared__ float LacT[16*32], LalT[16*32];
  __shared__ float ivr[4*32], ivc[2*16];
  const int lb = blockIdx.x, b = b0 + lb, tid = threadIdx.x;
  const float* ac  = a_cur  + (size_t)b*480;
  const float* as_ = a_slot + (size_t)b*900;
  const float* al  = a_last + (size_t)b*480;
  const float* ad  = a_dom  + (size_t)b*900;

  if (tid < 30) {
    float s1=0, s3=0;
    for (int c=0;c<16;c++){ s1+=ac[tid*16+c]; s3+=al[tid*16+c]; }
    ivr[tid] = 1.f/(s1+EPS_F); ivr[32+tid] = 1.f/(s3+EPS_F);
    float s2=0, s4=0;
    for (int j=0;j<30;j++){ s2+=as_[tid*30+j]; s4+=ad[tid*30+j]; }
    ivr[64+tid] = 1.f/(s2+EPS_F); ivr[96+tid] = 1.f/(s4+EPS_F);
  } else if (tid < 46) {
    int c = tid - 30; float s1=0, s3=0;
    for (int s=0;s<30;s++){ s1+=ac[s*16+c]; s3+=al[s*16+c]; }
    ivc[c] = 1.f/(s1+EPS_F); ivc[16+c] = 1.f/(s3+EPS_F);
  }
  __syncthreads();
  for (int i = tid; i < 480; i += 256) {
    int s = i >> 4;
    Lac[i] = ac[i]*ivr[s];
    Lal[i] = al[i]*ivr[32+s];
  }
  for (int i = tid; i < 960; i += 256) {
    int s = i >> 5, j = i & 31;
    Las[i] = (j < 30) ? as_[s*30+j]*ivr[64+s] : 0.f;
    Lad[i] = (j < 30) ? ad[s*30+j]*ivr[96+s] : 0.f;
  }
  for (int i = tid; i < 512; i += 256) {
    int c = i >> 5, s = i & 31;
    LacT[i] = (s < 30) ? ac[s*16+c]*ivc[c]    : 0.f;
    LalT[i] = (s < 30) ? al[s*16+c]*ivc[16+c] : 0.f;
  }
  __syncthreads();

  float xs[3][32], xc[3][16];
  #pragma unroll
  for (int j = 0; j < 3; ++j) {
    const int h = tid + j*256;
    #pragma unroll
    for (int s = 0; s < 30; ++s) xs[j][s] = slots[((size_t)b*30 + s)*768 + h];
    xs[j][30] = 0.f; xs[j][31] = 0.f;
    #pragma unroll
    for (int c = 0; c < 16; ++c) xc[j][c] = cls[((size_t)b*16 + c)*768 + h];
  }
  #pragma unroll
  for (int j = 0; j < 3; ++j) {
    const int h = tid + j*256;
    bf16* Gs = Gin + ((size_t)lb*30)*1536 + 768 + h;
    #pragma unroll
    for (int s = 0; s < 30; ++s) Gs[(size_t)s*1536] = __float2bfloat16(xs[j][s]);
    bf16* Gc = Gin + ((size_t)(rsBase + lb*16))*1536 + 768 + h;
    #pragma unroll
    for (int c = 0; c < 16; ++c) Gc[(size_t)c*1536] = __float2bfloat16(xc[j][c]);
  }

  #pragma unroll 2
  for (int s = 0; s < 30; ++s) {
    float a1[3] = {}, a2[3] = {}, a3[3] = {}, a4[3] = {};
    #pragma unroll
    for (int q = 0; q < 4; ++q) {
      float4 va = *(const float4*)&Lac[s*16 + q*4];
      float4 vl = *(const float4*)&Lal[s*16 + q*4];
      #pragma unroll
      for (int j = 0; j < 3; ++j) {
        a1[j] += va.x*xc[j][q*4] + va.y*xc[j][q*4+1] + va.z*xc[j][q*4+2] + va.w*xc[j][q*4+3];
        a3[j] += vl.x*xc[j][q*4] + vl.y*xc[j][q*4+1] + vl.z*xc[j][q*4+2] + vl.w*xc[j][q*4+3];
      }
    }
    #pragma unroll
    for (int q = 0; q < 8; ++q) {
      float4 vs = *(const float4*)&Las[s*32 + q*4];
      float4 vd = *(const float4*)&Lad[s*32 + q*4];
      #pragma unroll
      for (int j = 0; j < 3; ++j) {
        a2[j] += vs.x*xs[j][q*4] + vs.y*xs[j][q*4+1] + vs.z*xs[j][q*4+2] + vs.w*xs[j][q*4+3];
        a4[j] += vd.x*xs[j][q*4] + vd.y*xs[j][q*4+1] + vd.z*xs[j][q*4+2] + vd.w*xs[j][q*4+3];
      }
    }
    char* Zrow = (char*)Zs + (((size_t)lb*30 + s)*3072)*2;
    #pragma unroll
    for (int j = 0; j < 3; ++j) {
      const int h = tid + j*256;
      union { bf16 hv[4]; uint2 u; } p;
      p.hv[0] = __float2bfloat16(a1[j]);
      p.hv[1] = __float2bfloat16(a2[j]);
      p.hv[2] = __float2bfloat16(a3[j]);
      p.hv[3] = __float2bfloat16(a4[j]);
      *(uint2*)(Zrow + (size_t)h*8) = p.u;
    }
  }
  #pragma unroll 2
  for (int c = 0; c < 16; ++c) {
    float a1[3] = {}, a3[3] = {};
    #pragma unroll
    for (int q = 0; q < 8; ++q) {
      float4 va = *(const float4*)&LacT[c*32 + q*4];
      float4 vl = *(const float4*)&LalT[c*32 + q*4];
      #pragma unroll
      for (int j = 0; j < 3; ++j) {
        a1[j] += va.x*xs[j][q*4] + va.y*xs[j][q*4+1] + va.z*xs[j][q*4+2] + va.w*xs[j][q*4+3];
        a3[j] += vl.x*xs[j][q*4] + vl.y*xs[j][q*4+1] + vl.z*xs[j][q*4+2] + vl.w*xs[j][q*4+3];
      }
    }
    char* Zrow = (char*)Zc + (((size_t)lb*16 + c)*1536)*2;
    #pragma unroll
    for (int j = 0; j < 3; ++j) {
      const int h = tid + j*256;
      union { bf16 hv[2]; unsigned u; } p;
      p.hv[0] = __float2bfloat16(a1[j]);
      p.hv[1] = __float2bfloat16(a3[j]);
      *(unsigned*)(Zrow + (size_t)h*4) = p.u;
    }
  }
}

// ------------------------------------------------------------------
// layer-2 aggregation (cls rows only) from layer-1 slot state Xo (bf16).
// ------------------------------------------------------------------
__global__ __launch_bounds__(256) void agg2_k(
    const bf16* __restrict__ Xo,
    const float* __restrict__ a_cur, const float* __restrict__ a_last,
    bf16* __restrict__ Zc, int b0)
{
  __shared__ float LacT[16*32], LalT[16*32];
  __shared__ float ivc[2*16];
  const int lb = blockIdx.x, b = b0 + lb, tid = threadIdx.x;
  const float* ac = a_cur  + (size_t)b*480;
  const float* al = a_last + (size_t)b*480;
  if (tid < 16) {
    float s1=0, s3=0;
    for (int s=0;s<30;s++){ s1+=ac[s*16+tid]; s3+=al[s*16+tid]; }
    ivc[tid] = 1.f/(s1+EPS_F); ivc[16+tid] = 1.f/(s3+EPS_F);
  }
  __syncthreads();
  for (int i = tid; i < 512; i += 256) {
    int c = i >> 5, s = i & 31;
    LacT[i] = (s < 30) ? ac[s*16+c]*ivc[c]    : 0.f;
    LalT[i] = (s < 30) ? al[s*16+c]*ivc[16+c] : 0.f;
  }
  __syncthreads();

  float xs[3][32];
  #pragma unroll
  for (int j = 0; j < 3; ++j) {
    const int h = tid + j*256;
    #pragma unroll
    for (int s = 0; s < 30; ++s)
      xs[j][s] = __bfloat162float(Xo[((size_t)(lb*30 + s))*768 + h]);
    xs[j][30] = 0.f; xs[j][31] = 0.f;
  }
  #pragma unroll 2
  for (int c = 0; c < 16; ++c) {
    float a1[3] = {}, a3[3] = {};
    #pragma unroll
    for (int q = 0; q < 8; ++q) {
      float4 va = *(const float4*)&LacT[c*32 + q*4];
      float4 vl = *(const float4*)&LalT[c*32 + q*4];
      #pragma unroll
      for (int j = 0; j < 3; ++j) {
        a1[j] += va.x*xs[j][q*4] + va.y*xs[j][q*4+1] + va.z*xs[j][q*4+2] + va.w*xs[j][q*4+3];
        a3[j] += vl.x*xs[j][q*4] + vl.y*xs[j][q*4+1] + vl.z*xs[j][q*4+2] + vl.w*xs[j][q*4+3];
      }
    }
    char* Zrow = (char*)Zc + (((size_t)lb*16 + c)*1536)*2;
    #pragma unroll
    for (int j = 0; j < 3; ++j) {
      const int h = tid + j*256;
      union { bf16 hv[2]; unsigned u; } p;
      p.hv[0] = __float2bfloat16(a1[j]);
      p.hv[1] = __float2bfloat16(a3[j]);
      *(unsigned*)(Zrow + (size_t)h*4) = p.u;
    }
  }
}

// ------------------------------------------------------------------
// GEMM body: one 64x128 tile (BM=64, BN=128, BK=64) of A[M x K] @
// Bt[768 x K]^T. Smaller tile -> 2x grid, 24 KB LDS -> 6 blocks/CU cap;
// at ~4.3 co-resident blocks/CU the inter-block overlap (m114) hides
// the 2-phase barrier drain that 2.16 blocks/CU could not.
// T2 both-sides XOR swizzle. DBUF=true: 2-phase prefetch (small grids).
// 4 waves in 2x2: each wave 32 rows x 64 cols (acc 2x4).
// EPI 0: proj -> G left half = bf16(v + bias[col])
// EPI 1: gate -> Xo bf16; rows>=rsB also G2 right half (new cls x)
// EPI 2: gate -> out f32 (cls rows; skip c==0)
// ------------------------------------------------------------------
template<int K, int EPI, int LDA0, int LDA1, int SK, bool DBUF>
__device__ __forceinline__ void gemm_body(
    bf16* __restrict__ As, bf16* __restrict__ Bs, int wg,
    const bf16* __restrict__ A0, const bf16* __restrict__ A1,
    const bf16* __restrict__ Bt, bf16* __restrict__ G,
    bf16* __restrict__ G2, bf16* __restrict__ Xo, float* __restrict__ out,
    const float* __restrict__ bias, const float* __restrict__ bg,
    int b0, int rsB)
{
  const int tid  = threadIdx.x;
  const int lane = tid & 63;
  const int wave = tid >> 6;
  const int wm = wave >> 1, wn = wave & 1;   // 2x2 wave grid
  const int bm = wg / 6, bn = wg % 6;        // BN=128 -> 6 n-tiles

  const int swz = (((tid & 7) ^ ((tid >> 3) & 7))) << 3;   // elements
  const bf16* Ag0 = A0 + (size_t)(bm*64 + (tid>>3))*LDA0 + swz;
  const bf16* Ag1 = A1 + (size_t)(bm*64 + (tid>>3))*LDA1 + swz;
  const bf16* Bg  = Bt + (size_t)(bn*128 + (tid>>3))*K   + swz;
  const int ldsw = (wave*8)*64;              // wave-uniform LDS base

  f32x4 acc[2][4] = {};
  const int NT = K/64;

  auto stage = [&](int buf, int kt) {
    #pragma unroll
    for (int p = 0; p < 2; ++p) {            // A: 64 rows = 2 issues
      const bf16* asrc = (kt < SK) ? (Ag0 + (size_t)(p*32)*LDA0 + kt)
                                   : (Ag1 + (size_t)(p*32)*LDA1 + (kt - SK));
      __builtin_amdgcn_global_load_lds(
        (const __attribute__((address_space(1))) void*)asrc,
        (__attribute__((address_space(3))) void*)(&As[buf*4096 + ldsw + p*2048]), 16, 0, 0);
    }
    #pragma unroll
    for (int p = 0; p < 4; ++p) {            // B: 128 rows = 4 issues
      __builtin_amdgcn_global_load_lds(
        (const __attribute__((address_space(1))) void*)(Bg + (size_t)(p*32)*K + kt),
        (__attribute__((address_space(3))) void*)(&Bs[buf*8192 + ldsw + p*2048]), 16, 0, 0);
    }
  };

  auto compute = [&](int buf) {
    const bf16* Asb = As + buf*4096;
    const bf16* Bsb = Bs + buf*8192;
    #pragma unroll
    for (int ks = 0; ks < 64; ks += 32) {
      bf16x8 afv[2], bfv[4];
      const int sa = ((((ks >> 3) + (lane >> 4)) ^ (lane & 7))) << 3;
      #pragma unroll
      for (int i = 0; i < 2; ++i) {
        int m = wm*32 + i*16 + (lane & 15);
        afv[i] = *(const bf16x8*)&Asb[m*64 + sa];
      }
      #pragma unroll
      for (int j = 0; j < 4; ++j) {
        int n = wn*64 + j*16 + (lane & 15);
        bfv[j] = *(const bf16x8*)&Bsb[n*64 + sa];
      }
      #pragma unroll
      for (int i = 0; i < 2; ++i)
        #pragma unroll
        for (int j = 0; j < 4; ++j)
          acc[i][j] = __builtin_amdgcn_mfma_f32_16x16x32_bf16(afv[i], bfv[j], acc[i][j], 0, 0, 0);
    }
  };

  if constexpr (DBUF) {
    stage(0, 0);
    __syncthreads();
    int cur = 0;
    #pragma unroll 1
    for (int t = 0; t < NT; ++t) {
      if (t + 1 < NT) stage(cur ^ 1, (t + 1)*64);  // prefetch under MFMA
      compute(cur);
      __syncthreads();
      cur ^= 1;
    }
  } else {
    #pragma unroll 1
    for (int t = 0; t < NT; ++t) {
      stage(0, t*64);
      __syncthreads();     // loads landed
      compute(0);
      __syncthreads();     // reads done before next overwrite
    }
  }

  const int rbase = bm*64 + wm*32 + ((lane>>4)<<2);
  const int cbase = bn*128 + wn*64 + (lane & 15);
  #pragma unroll
  for (int i = 0; i < 2; ++i) {
    #pragma unroll
    for (int j = 0; j < 4; ++j) {
      const int col = cbase + j*16;
      #pragma unroll
      for (int r2 = 0; r2 < 4; ++r2) {
        const int row = rbase + i*16 + r2;
        float v = acc[i][j][r2];
        if constexpr (EPI == 0) {
          G[(size_t)row*1536 + col] = __float2bfloat16(v + bias[col]);
        } else if constexpr (EPI == 1) {
          v += bg[col];
          float g = 1.f/(1.f + __expf(-v));
          float u = __bfloat162float(G[(size_t)row*1536 + col]);
          float x = __bfloat162float(G[(size_t)row*1536 + 768 + col]);
          bf16 nv = __float2bfloat16(fmaxf(u, 0.f)*g + x*(1.f - g));
          Xo[(size_t)row*H_D + col] = nv;
          if (row >= rsB)
            G2[((size_t)(row - rsB))*1536 + 768 + col] = nv;
        } else { // EPI == 2
          v += bg[col];
          float g = 1.f/(1.f + __expf(-v));
          float u = __bfloat162float(G[(size_t)row*1536 + col]);
          int bb = row >> 4, c = row & 15;
          if (c >= 1) {
            float x = __bfloat162float(Xo[(size_t)row*H_D + col]);
            out[((size_t)(b0 + bb)*15 + (c - 1))*H_D + col] =
                fmaxf(u, 0.f)*g + x*(1.f - g);
          }
        }
      }
    }
  }
}

// T1 bijective XCD-chunked swizzle (m204)
__device__ __forceinline__ int xcd_swizzle(int bid, int nwg) {
  const int q = nwg >> 3, r = nwg & 7;
  const int xcd = bid & 7, idx = bid >> 3;
  return (xcd < r ? xcd*(q+1) : r*(q+1) + (xcd-r)*q) + idx;
}

// Standalone GEMM kernel
template<int K, int EPI, int LDA0, int LDA1, int SK, bool DBUF>
__global__ __launch_bounds__(256) void gemm_k(
    const bf16* __restrict__ A0, const bf16* __restrict__ A1,
    const bf16* __restrict__ Bt, bf16* __restrict__ G,
    bf16* __restrict__ G2, bf16* __restrict__ Xo, float* __restrict__ out,
    const float* __restrict__ bias, const float* __restrict__ bg,
    int b0, int rsB)
{
  __shared__ __align__(16) bf16 As[(DBUF ? 2 : 1)*64*64];
  __shared__ __align__(16) bf16 Bs[(DBUF ? 2 : 1)*128*64];
  int wg = xcd_swizzle(blockIdx.x, gridDim.x);
  gemm_body<K, EPI, LDA0, LDA1, SK, DBUF>(As, Bs, wg, A0, A1, Bt, G, G2, Xo,
                                          out, bias, bg, b0, rsB);
}

// Merged layer-1 projection: blocks [0,nS) slot proj (K=3840),
// [nS, nS+nC) cls proj (K=2304). Single-buffer 24 KB LDS, one launch.
__global__ __launch_bounds__(256) void proj1_k(
    const bf16* __restrict__ GinSx, const bf16* __restrict__ Zs,
    const bf16* __restrict__ Wcat,  bf16* __restrict__ GS,
    const bf16* __restrict__ GinCx, const bf16* __restrict__ Zc,
    const bf16* __restrict__ Wcat2, bf16* __restrict__ GC,
    const float* __restrict__ bslot, const float* __restrict__ bcls, int nS)
{
  __shared__ __align__(16) bf16 As[64*64];
  __shared__ __align__(16) bf16 Bs[128*64];
  int wg = xcd_swizzle(blockIdx.x, gridDim.x);
  if (wg < nS) {
    gemm_body<3840, 0, 1536, 3072, 768, false>(As, Bs, wg, GinSx, Zs, Wcat, GS,
        nullptr, nullptr, nullptr, bslot, nullptr, 0, 0);
  } else {
    gemm_body<2304, 0, 1536, 1536, 768, false>(As, Bs, wg - nS, GinCx, Zc, Wcat2, GC,
        nullptr, nullptr, nullptr, bcls, nullptr, 0, 0);
  }
}

// ------------------------------------------------------------------
extern "C" void kernel_launch(void* const* d_in, const int* in_sizes, int n_in,
                              void* d_out, int out_size, void* d_ws, size_t ws_size,
                              hipStream_t stream)
{
  const float* slots  = (const float*)d_in[0];
  const float* cls    = (const float*)d_in[1];
  const float* a_cur  = (const float*)d_in[2];
  const float* a_slot = (const float*)d_in[3];
  const float* a_last = (const float*)d_in[4];
  const float* a_dom  = (const float*)d_in[5];
  const float* W_r    = (const float*)d_in[6];
  const float* b_r    = (const float*)d_in[7];
  const float* W_s    = (const float*)d_in[8];
  const float* b_s    = (const float*)d_in[9];
  const float* W_g    = (const float*)d_in[10];
  const float* b_g    = (const float*)d_in[11];
  float* out = (float*)d_out;

  char* base = (char*)d_ws;
  size_t off = 0;
  auto alloc = [&](size_t bytes) -> void* {
    void* r = base + off;
    off = (off + bytes + 255) & ~(size_t)255;
    return r;
  };

  bf16* Wcat   = (bf16*)alloc((size_t)768*3840*2);
  bf16* Wg     = (bf16*)alloc((size_t)768*1536*2);
  bf16* Wcat2  = (bf16*)alloc((size_t)768*2304*2);
  float* bslot = (float*)alloc(768*4);
  float* bcls  = (float*)alloc(768*4);
  size_t fixedOff = off;

  // per-batch: Gin [46x1536] + Zs [30x3072] + Zc [16x1536], bf16.
  // Xo and GinC2 ALIAS into Zs (dead after proj1).
  const size_t perBatch = (size_t)46*1536*2 + (size_t)30*3072*2 + (size_t)16*1536*2;
  int chunkB = 512;
  while (chunkB > 64 && fixedOff + perBatch*(size_t)chunkB + 65536 > ws_size) chunkB >>= 1;

  const int rows_s = chunkB * S_D;
  const int rows_c = chunkB * C_D;
  const int rows_a = chunkB * (S_D + C_D);
  bf16* Gin = (bf16*)alloc((size_t)rows_a*1536*2);
  bf16* Zs  = (bf16*)alloc((size_t)rows_s*3072*2);
  bf16* Zc  = (bf16*)alloc((size_t)rows_c*1536*2);
  bf16* GinC = Gin + (size_t)rows_s*1536;
  bf16* Xo    = Zs;                                   // alias (Zs dead post-proj1)
  bf16* XoC   = Xo + (size_t)rows_s*768;
  bf16* GinC2 = Zs + (size_t)rows_a*768;              // alias, disjoint from Xo

  {
    int tot = 768*3840 + 768*1536 + 768*2304 + 768;
    prep_weights_k<<<(tot+255)/256, 256, 0, stream>>>(W_r, b_r, W_s, b_s, W_g,
                                                      Wcat, Wg, Wcat2, bslot, bcls);
  }

  for (int b0 = 0; b0 < 512; b0 += chunkB) {
    const int nS = (rows_s/64)*6, nC = (rows_c/64)*6;
    // ---- layer 1 ----
    agg1_k<<<chunkB, 256, 0, stream>>>(slots, cls, a_cur, a_slot, a_last, a_dom,
                                       Gin, Zs, Zc, b0, rows_s);
    // merged slot+cls proj (BM=64: 2x grid, all blocks co-resident)
    proj1_k<<<nS + nC, 256, 0, stream>>>(Gin + 768, Zs, Wcat, Gin,
                                         GinC + 768, Zc, Wcat2, GinC,
                                         bslot, bcls, nS);
    // gate (all rows): A = Gin = [u | x] -> Xo; cls rows also -> GinC2 right
    gemm_k<1536, 1, 1536, 1536, 1536, false><<<(rows_a/64)*6, 256, 0, stream>>>(
        Gin, Gin, Wg, Gin, GinC2, Xo, out, bslot, b_g, b0, rows_s);
    // ---- layer 2 (cls rows only; small grids -> dbuf prefetch) ----
    agg2_k<<<chunkB, 256, 0, stream>>>(Xo, a_cur, a_last, Zc, b0);
    gemm_k<2304, 0, 1536, 1536, 768, true><<<nC, 256, 0, stream>>>(
        GinC2 + 768, Zc, Wcat2, GinC2, nullptr, XoC, out, bcls, b_g, b0, 0);
    // final gate -> out
    gemm_k<1536, 2, 1536, 1536, 1536, true><<<nC, 256, 0, stream>>>(
        GinC2, GinC2, Wg, GinC2, nullptr, XoC, out, bcls, b_g, b0, 0);
  }
}